// Round 7
// baseline (716.326 us; speedup 1.0000x reference)
//
#include <hip/hip_runtime.h>
#include <math.h>

#define N_NODES 100000
#define E_EDGES 3200000
#define IN_DIM_ 128
#define HID_ 64
#define BN_EPS_ 1e-5f

#define PB 250          // edge-chunk blocks
#define CHUNK 12800     // E / PB exactly
#define NBUCK 391       // ceil(N / 256): bucket = dst >> 8
#define BMAX 9600       // passB LDS capacity (bucket mean 8184, 15 sigma)
#define SUB (N_NODES + 1)   // rows per feature-subtable (incl zero row)

typedef __attribute__((ext_vector_type(8))) short short8;
typedef __attribute__((ext_vector_type(4))) float f32x4;
typedef __attribute__((ext_vector_type(2))) float f32x2;

__device__ inline ushort f2bf(float f) {
    union { float f; unsigned u; } c; c.f = f;
    unsigned r = c.u + 0x7fff + ((c.u >> 16) & 1);   // RNE
    return (ushort)(r >> 16);
}
__device__ inline f32x2 up2(unsigned u) {
    union { unsigned u; float f; } lo, hi;
    lo.u = u << 16; hi.u = u & 0xffff0000u;
    f32x2 r; r.x = lo.f; r.y = hi.f; return r;
}

// ---------------- pass A1: per-block bucket histogram (+ zero deg) ---------
__global__ __launch_bounds__(512) void passA1_hist(const int* __restrict__ ei,
                                                   int* __restrict__ histPB,
                                                   int* __restrict__ deg) {
    __shared__ int hist[NBUCK];
    int t = threadIdx.x, b = blockIdx.x;
    int g = b * 512 + t;
    if (g < N_NODES) deg[g] = 0;          // 250*512 = 128000 >= N
    for (int k = t; k < NBUCK; k += 512) hist[k] = 0;
    __syncthreads();
    int e0 = b * CHUNK, e1 = e0 + CHUNK;
    for (int e = e0 + t; e < e1; e += 512) {
        int d = ei[E_EDGES + e];
        atomicAdd(&hist[d >> 8], 1);
    }
    __syncthreads();
    for (int k = t; k < NBUCK; k += 512) histPB[k * PB + b] = hist[k];
}

// ---------------- exact per-node degree ----------------
__global__ __launch_bounds__(256) void deg_hist(const int* __restrict__ ei,
                                                int* __restrict__ deg) {
    int stride = gridDim.x * 256;
    for (int e = blockIdx.x * 256 + threadIdx.x; e < E_EDGES; e += stride)
        atomicAdd(&deg[ei[E_EDGES + e]], 1);
}

// ---------------- per-bucket row scan (ebuf addressing) ----------------
__global__ __launch_bounds__(256) void scan_rows(int* __restrict__ histPB,
                                                 int* __restrict__ bucket_tot) {
    __shared__ int wsum[4];
    int k = blockIdx.x, t = threadIdx.x, lane = t & 63, wv = t >> 6;
    int v = (t < PB) ? histPB[k * PB + t] : 0;
    int s = v;
#pragma unroll
    for (int off = 1; off < 64; off <<= 1) {
        int u = __shfl_up(s, off, 64);
        if (lane >= off) s += u;
    }
    if (lane == 63) wsum[wv] = s;
    __syncthreads();
    int wbase = 0;
    for (int w = 0; w < wv; w++) wbase += wsum[w];
    if (t < PB) histPB[k * PB + t] = wbase + s - v;
    if (t == 255) bucket_tot[k] = wbase + s;
}

// ---------------- per-bucket padded totals (+ dinv) ----------------
__global__ __launch_bounds__(256) void pad_tot_k(const int* __restrict__ deg,
                                                 int* __restrict__ bucket_ptot,
                                                 float* __restrict__ dinv) {
    __shared__ int wsum[4];
    int b = blockIdx.x, t = threadIdx.x, lane = t & 63, wv = t >> 6;
    int node = b * 256 + t;
    int d = (node < N_NODES) ? deg[node] : 0;
    if (node < N_NODES) dinv[node] = rsqrtf((float)d + 1.0f);
    int pd = (d + 7) & ~7;
#pragma unroll
    for (int off = 1; off < 64; off <<= 1) pd += __shfl_xor(pd, off, 64);
    if (lane == 0) wsum[wv] = pd;
    __syncthreads();
    if (t == 0) bucket_ptot[b] = wsum[0] + wsum[1] + wsum[2] + wsum[3];
}

// ---------- dual scan of bucket totals (unpadded ebuf + padded csr) --------
__global__ __launch_bounds__(512) void scan_totals2(const int* __restrict__ bucket_tot,
                                                    const int* __restrict__ bucket_ptot,
                                                    int* __restrict__ bucket_base,
                                                    int* __restrict__ bucket_pbase,
                                                    int* __restrict__ row_ptr,
                                                    float* __restrict__ hs3) {
    __shared__ int wsA[8], wsB[8];
    int t = threadIdx.x, lane = t & 63, wv = t >> 6;
    int va = (t < NBUCK) ? bucket_tot[t] : 0;
    int vb = (t < NBUCK) ? bucket_ptot[t] : 0;
    int sa = va, sb = vb;
#pragma unroll
    for (int off = 1; off < 64; off <<= 1) {
        int ua = __shfl_up(sa, off, 64);
        int ub = __shfl_up(sb, off, 64);
        if (lane >= off) { sa += ua; sb += ub; }
    }
    if (lane == 63) { wsA[wv] = sa; wsB[wv] = sb; }
    __syncthreads();
    int wa = 0, wb = 0;
    for (int w = 0; w < wv; w++) { wa += wsA[w]; wb += wsB[w]; }
    if (t < NBUCK) {
        bucket_base[t]  = wa + sa - va;
        bucket_pbase[t] = wb + sb - vb;
    }
    if (t == NBUCK - 1) row_ptr[N_NODES] = wb + sb;   // padded total
    if (t == 0) {
        bucket_base[NBUCK] = E_EDGES;
        hs3[N_NODES] = 0.f;                           // sentinel target for gather3
    }
}

// ---- pass A2: LDS counting sort per chunk -> COALESCED ebuf writes ----
__global__ __launch_bounds__(512) void passA2_sorted(const int* __restrict__ ei,
                                                     const int* __restrict__ histPB,
                                                     const int* __restrict__ bucket_base,
                                                     int* __restrict__ ebuf) {
    __shared__ int sorted[CHUNK];     // 51.2 KB
    __shared__ ushort bid[CHUNK];     // 25.6 KB
    __shared__ int cur[NBUCK];
    __shared__ int lbase[NBUCK];
    int t = threadIdx.x, b = blockIdx.x;
    for (int k = t; k < NBUCK; k += 512) cur[k] = 0;
    __syncthreads();
    int e0 = b * CHUNK;
    for (int e = e0 + t; e < e0 + CHUNK; e += 512)
        atomicAdd(&cur[ei[E_EDGES + e] >> 8], 1);
    __syncthreads();
    if (t < 64) {
        int run = 0;
        for (int c0 = 0; c0 < NBUCK; c0 += 64) {
            int idx = c0 + t;
            int v = (idx < NBUCK) ? cur[idx] : 0;
            int s = v;
#pragma unroll
            for (int off = 1; off < 64; off <<= 1) {
                int u = __shfl_up(s, off, 64);
                if (t >= off) s += u;
            }
            if (idx < NBUCK) lbase[idx] = run + s - v;
            run += __shfl(s, 63, 64);
        }
    }
    __syncthreads();
    for (int k = t; k < NBUCK; k += 512) cur[k] = lbase[k];
    __syncthreads();
    for (int e = e0 + t; e < e0 + CHUNK; e += 512) {
        int s = ei[e];
        int d = ei[E_EDGES + e];
        int k = d >> 8;
        int pos = atomicAdd(&cur[k], 1);
        sorted[pos] = s | ((d & 255) << 17);
        bid[pos] = (ushort)k;
    }
    __syncthreads();
    for (int j = t; j < CHUNK; j += 512) {
        int k = bid[j];
        int dest = bucket_base[k] + histPB[k * PB + b] + (j - lbase[k]);
        ebuf[dest] = sorted[j];
    }
}

// ---- pass B: bucket sort -> PADDED csr (rows padded to x8 with sentinel) ---
__global__ __launch_bounds__(256) void passB_sorted(const int* __restrict__ ebuf,
                                                    const int* __restrict__ bucket_base,
                                                    const int* __restrict__ bucket_pbase,
                                                    const int* __restrict__ deg,
                                                    int* __restrict__ row_ptr,
                                                    int* __restrict__ csr_src) {
    __shared__ int sorted[BMAX];      // 38.4 KB
    __shared__ int ucur[256];
    __shared__ int ubeg[256];
    __shared__ int pbeg[256];
    __shared__ int wsA[4], wsB[4];
    int b = blockIdx.x, t = threadIdx.x, lane = t & 63, wv = t >> 6;
    int base = bucket_base[b], end = bucket_base[b + 1];
    int pbase = bucket_pbase[b];
    int node = b * 256 + t;
    int d = (node < N_NODES) ? deg[node] : 0;
    int pd = (d + 7) & ~7;
    int sa = d, sb = pd;
#pragma unroll
    for (int off = 1; off < 64; off <<= 1) {
        int ua = __shfl_up(sa, off, 64);
        int ub = __shfl_up(sb, off, 64);
        if (lane >= off) { sa += ua; sb += ub; }
    }
    if (lane == 63) { wsA[wv] = sa; wsB[wv] = sb; }
    __syncthreads();
    int wa = 0, wb = 0;
    for (int w = 0; w < wv; w++) { wa += wsA[w]; wb += wsB[w]; }
    int uex = wa + sa - d, pex = wb + sb - pd;
    ubeg[t] = uex; pbeg[t] = pex; ucur[t] = uex;
    if (node < N_NODES) row_ptr[node] = pbase + pex;
    __syncthreads();
    for (int k = base + t; k < end; k += 256) {
        int pv = ebuf[k];
        int pos = atomicAdd(&ucur[pv >> 17], 1);
        if (pos < BMAX) sorted[pos] = pv;    // overflow impossible (15 sigma)
    }
    __syncthreads();
    // write out padded rows: real entries then sentinel (zero-row) padding
    for (int r = wv; r < 256; r += 4) {
        int nd = b * 256 + r;
        int d2 = (nd < N_NODES) ? deg[nd] : 0;
        int pd2 = (d2 + 7) & ~7;
        int ub = ubeg[r], pb = pbeg[r];
        for (int c = lane; c < pd2; c += 64)
            csr_src[pbase + pb + c] = (c < d2) ? (sorted[ub + c] & 0x1FFFF) : N_NODES;
    }
}

// ------- pull-gather pass P: features [16P,16P+16) from L2-resident subtable
// Subtable_P = hs + P*SUB*16 bf16, rows of 32 B (3.2 MB < 4 MB L2/XCD).
// 64 lanes = 8 edge-slots (es) x 8 fg (4 B = 2 features each). Rows padded to
// x8 with sentinel N_NODES -> zero row: NO clamps/selects in the inner loop.
template<bool LAST, int P>
__global__ __launch_bounds__(256) void gather_pass(const int* __restrict__ row_ptr,
                                                   const int* __restrict__ csr_src,
                                                   const ushort* __restrict__ hs,
                                                   const float* __restrict__ dinv,
                                                   const float* __restrict__ b,
                                                   const float* __restrict__ g,
                                                   const float* __restrict__ beta,
                                                   const float* __restrict__ m,
                                                   const float* __restrict__ v,
                                                   unsigned* __restrict__ y,
                                                   const float* __restrict__ W3,
                                                   float* __restrict__ hs3, int n) {
    int i = (blockIdx.x * 256 + threadIdx.x) >> 6;
    if (i >= n) return;
    int l = threadIdx.x & 63;
    int es = l >> 3, fg = l & 7;

    const unsigned* T = (const unsigned*)hs + (long)P * SUB * 8;  // 8 uints/row

    f32x2 acc = {0.f, 0.f};
    if (es == 0) acc += up2(T[(unsigned)i * 8 + fg]);   // self-loop

    int pbeg = row_ptr[i], pend = row_ptr[i + 1];
    const int* cs = csr_src + pbeg;
    int nb8 = (pend - pbeg) >> 3;
    int k = es;
    int full = nb8 >> 2;
    for (int t = 0; t < full; t++, k += 32) {
        int s0 = cs[k], s1 = cs[k + 8], s2 = cs[k + 16], s3 = cs[k + 24];
        unsigned u0 = T[(unsigned)s0 * 8 + fg];
        unsigned u1 = T[(unsigned)s1 * 8 + fg];
        unsigned u2 = T[(unsigned)s2 * 8 + fg];
        unsigned u3 = T[(unsigned)s3 * 8 + fg];
        acc += up2(u0); acc += up2(u1); acc += up2(u2); acc += up2(u3);
    }
    for (int rem = nb8 & 3; rem > 0; rem--, k += 8) {
        int s = cs[k];
        acc += up2(T[(unsigned)s * 8 + fg]);
    }

    // reduce over es (lanes sharing fg)
#pragma unroll
    for (int off = 8; off < 64; off <<= 1) {
        acc.x += __shfl_xor(acc.x, off, 64);
        acc.y += __shfl_xor(acc.y, off, 64);
    }

    float2 bb = ((const float2*)b)[P * 8 + fg];
    float2 gg = ((const float2*)g)[P * 8 + fg];
    float2 be = ((const float2*)beta)[P * 8 + fg];
    float2 mm = ((const float2*)m)[P * 8 + fg];
    float2 vv = ((const float2*)v)[P * 8 + fg];
    float di = dinv[i];
    float o0 = fmaxf((di * acc.x + bb.x - mm.x) * (gg.x * rsqrtf(vv.x + BN_EPS_)) + be.x, 0.f);
    float o1 = fmaxf((di * acc.y + bb.y - mm.y) * (gg.y * rsqrtf(vv.y + BN_EPS_)) + be.y, 0.f);

    if (LAST) {
        float2 w3 = ((const float2*)W3)[P * 8 + fg];
        float p = o0 * w3.x + o1 * w3.y;
#pragma unroll
        for (int off = 1; off < 8; off <<= 1)
            p += __shfl_xor(p, off, 64);
        if (l == 0) {
            float prev = (P == 0) ? 0.f : hs3[i];
            float now = prev + p;
            hs3[i] = (P == 3) ? now * di : now;
        }
    } else {
        if (es == 0) {
            unsigned pk = (unsigned)f2bf(o0) | ((unsigned)f2bf(o1) << 16);
            y[(unsigned)i * 32 + P * 8 + fg] = pk;
        }
    }
}

// --------- MFMA GEMM: hs subtables (bf16) = (X @ W) * dinv[row] ------------
// Subtable layout: hs[c*SUB*16 + node*16 + m] holds feature 16c+m.
// Node N_NODES is a ZERO row in every subtable (gather sentinel target).
template<int K, bool BF16IN>
__global__ __launch_bounds__(256) void gemm_bf16(const void* __restrict__ Xv,
                                                 const float* __restrict__ W,   // [K][64]
                                                 const float* __restrict__ dinv,
                                                 ushort* __restrict__ hs) {
    constexpr int KP = K + 8;
    __shared__ ushort A_lds[64][KP];
    __shared__ ushort Wt_lds[64][KP];
    int t = threadIdx.x;
    long row0 = (long)blockIdx.x * 64;

    for (int i = t; i < K * 16; i += 256) {
        float4 w4 = ((const float4*)W)[i];
        int k = i >> 4, n = (i & 15) * 4;
        Wt_lds[n + 0][k] = f2bf(w4.x);
        Wt_lds[n + 1][k] = f2bf(w4.y);
        Wt_lds[n + 2][k] = f2bf(w4.z);
        Wt_lds[n + 3][k] = f2bf(w4.w);
    }
    if (BF16IN) {
        constexpr int K2 = K / 2;
        const unsigned* X = (const unsigned*)Xv;
        for (int i = t; i < 64 * K2; i += 256) {
            int r = i / K2, c = i % K2;
            unsigned val = 0;
            long row = row0 + r;
            if (row < N_NODES) val = X[row * K2 + c];
            *(unsigned*)&A_lds[r][c * 2] = val;
        }
    } else {
        constexpr int K4 = K / 4;
        const float* X = (const float*)Xv;
        for (int i = t; i < 64 * K4; i += 256) {
            int r = i / K4, c = i % K4;
            float4 val = make_float4(0.f, 0.f, 0.f, 0.f);
            long row = row0 + r;
            if (row < N_NODES) val = ((const float4*)X)[row * K4 + c];
            int cb = c * 4;
            A_lds[r][cb + 0] = f2bf(val.x);
            A_lds[r][cb + 1] = f2bf(val.y);
            A_lds[r][cb + 2] = f2bf(val.z);
            A_lds[r][cb + 3] = f2bf(val.w);
        }
    }
    __syncthreads();

    int w = t >> 6, l = t & 63;
    int m = l & 15, quad = l >> 4;
    f32x4 acc[4];
#pragma unroll
    for (int c = 0; c < 4; c++) acc[c] = (f32x4){0.f, 0.f, 0.f, 0.f};

#pragma unroll
    for (int ch = 0; ch < K / 32; ch++) {
        short8 a = *(const short8*)&A_lds[16 * w + m][32 * ch + 8 * quad];
#pragma unroll
        for (int c = 0; c < 4; c++) {
            short8 b = *(const short8*)&Wt_lds[16 * c + m][32 * ch + 8 * quad];
            acc[c] = __builtin_amdgcn_mfma_f32_16x16x32_bf16(a, b, acc[c], 0, 0, 0);
        }
    }

#pragma unroll
    for (int r = 0; r < 4; r++) {
        long node = row0 + 16 * w + quad * 4 + r;
        if (node <= N_NODES) {                       // include zero row N
            float dv = (node < N_NODES) ? dinv[node] : 0.f;
#pragma unroll
            for (int c = 0; c < 4; c++)
                hs[((long)c * SUB + node) * 16 + m] = f2bf(acc[c][r] * dv);
        }
    }
}

// ---------------- layer-3 pull + sigmoid (padded rows, hs3[N]=0) -----------
__global__ __launch_bounds__(256) void gather3(const int* __restrict__ row_ptr,
                                               const int* __restrict__ csr_src,
                                               const float* __restrict__ hs3,
                                               const float* __restrict__ dinv,
                                               const float* __restrict__ b3,
                                               float* __restrict__ out, int n) {
    int i = blockIdx.x * 256 + threadIdx.x;
    if (i >= n) return;
    int beg = row_ptr[i], end = row_ptr[i + 1];
    float s0 = hs3[i], s1 = 0.f, s2 = 0.f, s3 = 0.f;
    float s4 = 0.f, s5 = 0.f, s6 = 0.f, s7 = 0.f;
    for (int k = beg; k + 8 <= end; k += 8) {
        s0 += hs3[csr_src[k]];
        s1 += hs3[csr_src[k + 1]];
        s2 += hs3[csr_src[k + 2]];
        s3 += hs3[csr_src[k + 3]];
        s4 += hs3[csr_src[k + 4]];
        s5 += hs3[csr_src[k + 5]];
        s6 += hs3[csr_src[k + 6]];
        s7 += hs3[csr_src[k + 7]];
    }
    float z = dinv[i] * (((s0 + s1) + (s2 + s3)) + ((s4 + s5) + (s6 + s7))) + b3[0];
    out[i] = 1.f / (1.f + expf(-z));
}

extern "C" void kernel_launch(void* const* d_in, const int* in_sizes, int n_in,
                              void* d_out, int out_size, void* d_ws, size_t ws_size,
                              hipStream_t stream) {
    const int N = N_NODES;

    const float* x   = (const float*)d_in[0];
    const int*   ei  = (const int*)d_in[1];   // [2, E]: row0=src, row1=dst
    const float* W1  = (const float*)d_in[2];
    const float* b1  = (const float*)d_in[3];
    const float* W2  = (const float*)d_in[4];
    const float* b2  = (const float*)d_in[5];
    const float* W3  = (const float*)d_in[6];
    const float* b3  = (const float*)d_in[7];
    const float* g1  = (const float*)d_in[8];
    const float* bt1 = (const float*)d_in[9];
    const float* m1  = (const float*)d_in[10];
    const float* v1  = (const float*)d_in[11];
    const float* g2  = (const float*)d_in[12];
    const float* bt2 = (const float*)d_in[13];
    const float* m2  = (const float*)d_in[14];
    const float* v2  = (const float*)d_in[15];
    float* out = (float*)d_out;

    // workspace layout (4-byte units)
    int*    wsi          = (int*)d_ws;
    float*  dinv         = (float*)wsi;                       // N
    float*  hs3          = (float*)(wsi + (long)N);           // N+1 (pad 16)
    int*    row_ptr      = wsi + 2L * N + 16;                 // N+1 (pad 16)
    int*    deg          = row_ptr + N + 16;                  // N (pad 16)
    int*    histPB       = deg + N + 16;                      // NBUCK*PB = 97750
    int*    bucket_tot   = histPB + NBUCK * PB;               // 400
    int*    bucket_base  = bucket_tot + 400;                  // 401 (pad 400)
    int*    bucket_ptot  = bucket_base + 400;                 // 400
    int*    bucket_pbase = bucket_ptot + 400;                 // 400 (+2 align)
    ushort* hsb          = (ushort*)(bucket_pbase + 402);     // 4 subtables: SUB*32 ints
    unsigned* yb         = (unsigned*)((int*)(void*)hsb + 32L * SUB); // N*32 uints
    int*    csr_src      = (int*)yb + 32L * N;                // padded: up to E+8N
    int*    ebuf         = (int*)(void*)hsb;                  // E ints, aliases hsb (build only)

    // ---- CSR build (bucketed counting sort, padded rows, coalesced) ----
    passA1_hist<<<PB, 512, 0, stream>>>(ei, histPB, deg);
    deg_hist<<<1024, 256, 0, stream>>>(ei, deg);
    scan_rows<<<NBUCK, 256, 0, stream>>>(histPB, bucket_tot);
    pad_tot_k<<<NBUCK, 256, 0, stream>>>(deg, bucket_ptot, dinv);
    scan_totals2<<<1, 512, 0, stream>>>(bucket_tot, bucket_ptot, bucket_base,
                                        bucket_pbase, row_ptr, hs3);
    passA2_sorted<<<PB, 512, 0, stream>>>(ei, histPB, bucket_base, ebuf);
    passB_sorted<<<NBUCK, 256, 0, stream>>>(ebuf, bucket_base, bucket_pbase,
                                            deg, row_ptr, csr_src);

    const int GG = (N + 3) / 4;   // one row per wave

    // ---- layer 1: GEMM + 4 feature-split gather passes ----
    gemm_bf16<IN_DIM_, false><<<(N + 63) / 64, 256, 0, stream>>>(x, W1, dinv, hsb);
    gather_pass<false, 0><<<GG, 256, 0, stream>>>(row_ptr, csr_src, hsb, dinv,
                                                  b1, g1, bt1, m1, v1, yb, W3, hs3, N);
    gather_pass<false, 1><<<GG, 256, 0, stream>>>(row_ptr, csr_src, hsb, dinv,
                                                  b1, g1, bt1, m1, v1, yb, W3, hs3, N);
    gather_pass<false, 2><<<GG, 256, 0, stream>>>(row_ptr, csr_src, hsb, dinv,
                                                  b1, g1, bt1, m1, v1, yb, W3, hs3, N);
    gather_pass<false, 3><<<GG, 256, 0, stream>>>(row_ptr, csr_src, hsb, dinv,
                                                  b1, g1, bt1, m1, v1, yb, W3, hs3, N);
    // ---- layer 2: GEMM + 4 passes (fused gemv3 accumulation into hs3) ----
    gemm_bf16<HID_, true><<<(N + 63) / 64, 256, 0, stream>>>(yb, W2, dinv, hsb);
    gather_pass<true, 0><<<GG, 256, 0, stream>>>(row_ptr, csr_src, hsb, dinv,
                                                 b2, g2, bt2, m2, v2, yb, W3, hs3, N);
    gather_pass<true, 1><<<GG, 256, 0, stream>>>(row_ptr, csr_src, hsb, dinv,
                                                 b2, g2, bt2, m2, v2, yb, W3, hs3, N);
    gather_pass<true, 2><<<GG, 256, 0, stream>>>(row_ptr, csr_src, hsb, dinv,
                                                 b2, g2, bt2, m2, v2, yb, W3, hs3, N);
    gather_pass<true, 3><<<GG, 256, 0, stream>>>(row_ptr, csr_src, hsb, dinv,
                                                 b2, g2, bt2, m2, v2, yb, W3, hs3, N);
    // ---- layer 3 ----
    gather3<<<(N + 255) / 256, 256, 0, stream>>>(row_ptr, csr_src, hs3, dinv, b3, out, N);
}

// Round 9
// 489.936 us; speedup vs baseline: 1.4621x; 1.4621x over previous
//
#include <hip/hip_runtime.h>
#include <math.h>

#define N_NODES 100000
#define E_EDGES 3200000
#define IN_DIM_ 128
#define HID_ 64
#define BN_EPS_ 1e-5f

#define PB 250          // edge-chunk blocks
#define CHUNK 12800     // E / PB exactly
#define NBUCK 391       // ceil(N / 256): bucket = dst >> 8
#define BMAX 9600       // passB LDS capacity (bucket mean 8184, 15 sigma)
#define SUB (N_NODES + 1)   // rows per feature-subtable (incl zero row)

typedef __attribute__((ext_vector_type(8))) short short8;
typedef __attribute__((ext_vector_type(4))) float f32x4;

__device__ inline ushort f2bf(float f) {
    union { float f; unsigned u; } c; c.f = f;
    unsigned r = c.u + 0x7fff + ((c.u >> 16) & 1);   // RNE
    return (ushort)(r >> 16);
}
__device__ inline float bf_lo(unsigned p) { union { unsigned u; float f; } c; c.u = p << 16; return c.f; }
__device__ inline float bf_hi(unsigned p) { union { unsigned u; float f; } c; c.u = p & 0xffff0000u; return c.f; }

// ---------------- pass A1: per-block bucket histogram ----------------
__global__ __launch_bounds__(512) void passA1_hist(const int* __restrict__ ei,
                                                   int* __restrict__ histPB) {
    __shared__ int hist[NBUCK];
    int t = threadIdx.x, b = blockIdx.x;
    for (int k = t; k < NBUCK; k += 512) hist[k] = 0;
    __syncthreads();
    int e0 = b * CHUNK, e1 = e0 + CHUNK;
    for (int e = e0 + t; e < e1; e += 512) {
        int d = ei[E_EDGES + e];
        atomicAdd(&hist[d >> 8], 1);
    }
    __syncthreads();
    for (int k = t; k < NBUCK; k += 512) histPB[k * PB + b] = hist[k];
}

// ---------------- per-bucket row scan (ebuf addressing) ----------------
__global__ __launch_bounds__(256) void scan_rows(int* __restrict__ histPB,
                                                 int* __restrict__ bucket_tot) {
    __shared__ int wsum[4];
    int k = blockIdx.x, t = threadIdx.x, lane = t & 63, wv = t >> 6;
    int v = (t < PB) ? histPB[k * PB + t] : 0;
    int s = v;
#pragma unroll
    for (int off = 1; off < 64; off <<= 1) {
        int u = __shfl_up(s, off, 64);
        if (lane >= off) s += u;
    }
    if (lane == 63) wsum[wv] = s;
    __syncthreads();
    int wbase = 0;
    for (int w = 0; w < wv; w++) wbase += wsum[w];
    if (t < PB) histPB[k * PB + t] = wbase + s - v;
    if (t == 255) bucket_tot[k] = wbase + s;
}

// ---------------- scan bucket totals -> bucket_base (ebuf) ----------------
__global__ __launch_bounds__(512) void scan_totals(const int* __restrict__ bucket_tot,
                                                   int* __restrict__ bucket_base,
                                                   float* __restrict__ hs3) {
    __shared__ int wsum[8];
    int t = threadIdx.x, lane = t & 63, wv = t >> 6;
    int v = (t < NBUCK) ? bucket_tot[t] : 0;
    int s = v;
#pragma unroll
    for (int off = 1; off < 64; off <<= 1) {
        int u = __shfl_up(s, off, 64);
        if (lane >= off) s += u;
    }
    if (lane == 63) wsum[wv] = s;
    __syncthreads();
    int wbase = 0;
    for (int w = 0; w < wv; w++) wbase += wsum[w];
    if (t < NBUCK) bucket_base[t] = wbase + s - v;
    if (t == 0) {
        bucket_base[NBUCK] = E_EDGES;
        hs3[N_NODES] = 0.f;          // sentinel target for gather3
    }
}

// ---- pass A2: LDS counting sort per chunk -> COALESCED ebuf writes ----
__global__ __launch_bounds__(512) void passA2_sorted(const int* __restrict__ ei,
                                                     const int* __restrict__ histPB,
                                                     const int* __restrict__ bucket_base,
                                                     int* __restrict__ ebuf) {
    __shared__ int sorted[CHUNK];     // 51.2 KB
    __shared__ ushort bid[CHUNK];     // 25.6 KB
    __shared__ int cur[NBUCK];
    __shared__ int lbase[NBUCK];
    int t = threadIdx.x, b = blockIdx.x;
    for (int k = t; k < NBUCK; k += 512) cur[k] = 0;
    __syncthreads();
    int e0 = b * CHUNK;
    for (int e = e0 + t; e < e0 + CHUNK; e += 512)
        atomicAdd(&cur[ei[E_EDGES + e] >> 8], 1);
    __syncthreads();
    if (t < 64) {
        int run = 0;
        for (int c0 = 0; c0 < NBUCK; c0 += 64) {
            int idx = c0 + t;
            int v = (idx < NBUCK) ? cur[idx] : 0;
            int s = v;
#pragma unroll
            for (int off = 1; off < 64; off <<= 1) {
                int u = __shfl_up(s, off, 64);
                if (t >= off) s += u;
            }
            if (idx < NBUCK) lbase[idx] = run + s - v;
            run += __shfl(s, 63, 64);
        }
    }
    __syncthreads();
    for (int k = t; k < NBUCK; k += 512) cur[k] = lbase[k];
    __syncthreads();
    for (int e = e0 + t; e < e0 + CHUNK; e += 512) {
        int s = ei[e];
        int d = ei[E_EDGES + e];
        int k = d >> 8;
        int pos = atomicAdd(&cur[k], 1);
        sorted[pos] = s | ((d & 255) << 17);
        bid[pos] = (ushort)k;
    }
    __syncthreads();
    for (int j = t; j < CHUNK; j += 512) {
        int k = bid[j];
        int dest = bucket_base[k] + histPB[k * PB + b] + (j - lbase[k]);
        ebuf[dest] = sorted[j];
    }
}

// ---- bucket_deg: per-node degree via LDS counting over ebuf (NO global atomics)
__global__ __launch_bounds__(256) void bucket_deg(const int* __restrict__ ebuf,
                                                  const int* __restrict__ bucket_base,
                                                  int* __restrict__ deg,
                                                  float* __restrict__ dinv,
                                                  int* __restrict__ bucket_ptot) {
    __shared__ int hist[256];
    __shared__ int wsum[4];
    int b = blockIdx.x, t = threadIdx.x, lane = t & 63, wv = t >> 6;
    int base = bucket_base[b], end = bucket_base[b + 1];
    hist[t] = 0;
    __syncthreads();
    for (int k = base + t; k < end; k += 256)
        atomicAdd(&hist[ebuf[k] >> 17], 1);
    __syncthreads();
    int node = b * 256 + t;
    int d = hist[t];
    if (node < N_NODES) {
        deg[node] = d;
        dinv[node] = rsqrtf((float)d + 1.0f);
    }
    int pd = (node < N_NODES) ? ((d + 15) & ~15) : 0;
#pragma unroll
    for (int off = 1; off < 64; off <<= 1) pd += __shfl_xor(pd, off, 64);
    if (lane == 0) wsum[wv] = pd;
    __syncthreads();
    if (t == 0) bucket_ptot[b] = wsum[0] + wsum[1] + wsum[2] + wsum[3];
}

// ---------------- scan padded totals -> bucket_pbase ----------------
__global__ __launch_bounds__(512) void scan_ptot(const int* __restrict__ bucket_ptot,
                                                 int* __restrict__ bucket_pbase,
                                                 int* __restrict__ row_ptr) {
    __shared__ int wsum[8];
    int t = threadIdx.x, lane = t & 63, wv = t >> 6;
    int v = (t < NBUCK) ? bucket_ptot[t] : 0;
    int s = v;
#pragma unroll
    for (int off = 1; off < 64; off <<= 1) {
        int u = __shfl_up(s, off, 64);
        if (lane >= off) s += u;
    }
    if (lane == 63) wsum[wv] = s;
    __syncthreads();
    int wbase = 0;
    for (int w = 0; w < wv; w++) wbase += wsum[w];
    if (t < NBUCK) bucket_pbase[t] = wbase + s - v;
    if (t == NBUCK - 1) row_ptr[N_NODES] = wbase + s;
}

// ---- pass B: bucket sort -> PADDED csr (rows padded to x16 with sentinel) ---
__global__ __launch_bounds__(256) void passB_sorted(const int* __restrict__ ebuf,
                                                    const int* __restrict__ bucket_base,
                                                    const int* __restrict__ bucket_pbase,
                                                    const int* __restrict__ deg,
                                                    int* __restrict__ row_ptr,
                                                    int* __restrict__ csr_src) {
    __shared__ int sorted[BMAX];      // 38.4 KB
    __shared__ int ucur[256];
    __shared__ int ubeg[256];
    __shared__ int pbeg[256];
    __shared__ int wsA[4], wsB[4];
    int b = blockIdx.x, t = threadIdx.x, lane = t & 63, wv = t >> 6;
    int base = bucket_base[b], end = bucket_base[b + 1];
    int pbase = bucket_pbase[b];
    int node = b * 256 + t;
    int d = (node < N_NODES) ? deg[node] : 0;
    int pd = (d + 15) & ~15;
    if (node >= N_NODES) pd = 0;
    int sa = d, sb = pd;
#pragma unroll
    for (int off = 1; off < 64; off <<= 1) {
        int ua = __shfl_up(sa, off, 64);
        int ub = __shfl_up(sb, off, 64);
        if (lane >= off) { sa += ua; sb += ub; }
    }
    if (lane == 63) { wsA[wv] = sa; wsB[wv] = sb; }
    __syncthreads();
    int wa = 0, wb = 0;
    for (int w = 0; w < wv; w++) { wa += wsA[w]; wb += wsB[w]; }
    int uex = wa + sa - d, pex = wb + sb - pd;
    ubeg[t] = uex; pbeg[t] = pex; ucur[t] = uex;
    if (node < N_NODES) row_ptr[node] = pbase + pex;
    __syncthreads();
    for (int k = base + t; k < end; k += 256) {
        int pv = ebuf[k];
        int pos = atomicAdd(&ucur[pv >> 17], 1);
        if (pos < BMAX) sorted[pos] = pv;    // overflow ~impossible (15 sigma)
    }
    __syncthreads();
    // write out padded rows: real entries then sentinel (zero-row) padding
    for (int r = wv; r < 256; r += 4) {
        int nd = b * 256 + r;
        int d2 = (nd < N_NODES) ? deg[nd] : 0;
        int pd2 = (nd < N_NODES) ? ((d2 + 15) & ~15) : 0;
        int ub = ubeg[r], pb = pbeg[r];
        for (int c = lane; c < pd2; c += 64)
            csr_src[pbase + pb + c] = (c < d2) ? (sorted[ub + c] & 0x1FFFF) : N_NODES;
    }
}

// -- pull-gather pass P (P=0,1): features [32P,32P+32) from 6.4MB subtable --
// Subtable_P rows are 64 B; predicted L2 hit ~62% (4MB L2 / 6.4MB table).
// 64 lanes = 16 edge-slots (es) x 4 fg; fg lane loads uint4 (16 B) -> full
// 64 B row per es group; SAME total lane-gather count as the single-pass
// kernel. Rows padded to x16 with sentinel N_NODES (zero row): branch-free.
template<bool LAST, int P>
__global__ __launch_bounds__(256) void gather_pass(const int* __restrict__ row_ptr,
                                                   const int* __restrict__ csr_src,
                                                   const ushort* __restrict__ hs,
                                                   const float* __restrict__ dinv,
                                                   const float* __restrict__ b,
                                                   const float* __restrict__ g,
                                                   const float* __restrict__ beta,
                                                   const float* __restrict__ m,
                                                   const float* __restrict__ v,
                                                   unsigned* __restrict__ y,
                                                   const float* __restrict__ W3,
                                                   float* __restrict__ hs3, int n) {
    int i = (blockIdx.x * 256 + threadIdx.x) >> 6;
    if (i >= n) return;
    int l = threadIdx.x & 63;
    int es = l >> 2, fg = l & 3;

    const uint4* T4 = (const uint4*)((const unsigned*)hs + (long)P * SUB * 16);

    float a0 = 0.f, a1 = 0.f, a2 = 0.f, a3 = 0.f;
    float a4 = 0.f, a5 = 0.f, a6 = 0.f, a7 = 0.f;

    if (es == 0) {   // self-loop
        uint4 p = T4[(unsigned)i * 4 + fg];
        a0 += bf_lo(p.x); a1 += bf_hi(p.x);
        a2 += bf_lo(p.y); a3 += bf_hi(p.y);
        a4 += bf_lo(p.z); a5 += bf_hi(p.z);
        a6 += bf_lo(p.w); a7 += bf_hi(p.w);
    }

    int pbeg = row_ptr[i], pend = row_ptr[i + 1];
    const int* cs = csr_src + pbeg + es;
    int nb16 = (pend - pbeg) >> 4;
    int k = 0;
    for (; k + 2 <= nb16; k += 2) {
        int sA = cs[0];
        int sB = cs[16];
        cs += 32;
        uint4 pA = T4[(unsigned)sA * 4 + fg];
        uint4 pB = T4[(unsigned)sB * 4 + fg];
        a0 += bf_lo(pA.x) + bf_lo(pB.x); a1 += bf_hi(pA.x) + bf_hi(pB.x);
        a2 += bf_lo(pA.y) + bf_lo(pB.y); a3 += bf_hi(pA.y) + bf_hi(pB.y);
        a4 += bf_lo(pA.z) + bf_lo(pB.z); a5 += bf_hi(pA.z) + bf_hi(pB.z);
        a6 += bf_lo(pA.w) + bf_lo(pB.w); a7 += bf_hi(pA.w) + bf_hi(pB.w);
    }
    if (k < nb16) {
        int s = cs[0];
        uint4 p = T4[(unsigned)s * 4 + fg];
        a0 += bf_lo(p.x); a1 += bf_hi(p.x);
        a2 += bf_lo(p.y); a3 += bf_hi(p.y);
        a4 += bf_lo(p.z); a5 += bf_hi(p.z);
        a6 += bf_lo(p.w); a7 += bf_hi(p.w);
    }

    // reduce over es (16 slots; lanes sharing fg)
#pragma unroll
    for (int off = 4; off < 64; off <<= 1) {
        a0 += __shfl_xor(a0, off, 64);
        a1 += __shfl_xor(a1, off, 64);
        a2 += __shfl_xor(a2, off, 64);
        a3 += __shfl_xor(a3, off, 64);
        a4 += __shfl_xor(a4, off, 64);
        a5 += __shfl_xor(a5, off, 64);
        a6 += __shfl_xor(a6, off, 64);
        a7 += __shfl_xor(a7, off, 64);
    }

    int fb = P * 8 + fg * 2;   // float4-pair index: features [32P+8fg, +8)
    float4 bb0 = ((const float4*)b)[fb],    bb1 = ((const float4*)b)[fb + 1];
    float4 gg0 = ((const float4*)g)[fb],    gg1 = ((const float4*)g)[fb + 1];
    float4 be0 = ((const float4*)beta)[fb], be1 = ((const float4*)beta)[fb + 1];
    float4 mm0 = ((const float4*)m)[fb],    mm1 = ((const float4*)m)[fb + 1];
    float4 vv0 = ((const float4*)v)[fb],    vv1 = ((const float4*)v)[fb + 1];
    float di = dinv[i];
    float o0 = fmaxf((di * a0 + bb0.x - mm0.x) * (gg0.x * rsqrtf(vv0.x + BN_EPS_)) + be0.x, 0.f);
    float o1 = fmaxf((di * a1 + bb0.y - mm0.y) * (gg0.y * rsqrtf(vv0.y + BN_EPS_)) + be0.y, 0.f);
    float o2 = fmaxf((di * a2 + bb0.z - mm0.z) * (gg0.z * rsqrtf(vv0.z + BN_EPS_)) + be0.z, 0.f);
    float o3 = fmaxf((di * a3 + bb0.w - mm0.w) * (gg0.w * rsqrtf(vv0.w + BN_EPS_)) + be0.w, 0.f);
    float o4 = fmaxf((di * a4 + bb1.x - mm1.x) * (gg1.x * rsqrtf(vv1.x + BN_EPS_)) + be1.x, 0.f);
    float o5 = fmaxf((di * a5 + bb1.y - mm1.y) * (gg1.y * rsqrtf(vv1.y + BN_EPS_)) + be1.y, 0.f);
    float o6 = fmaxf((di * a6 + bb1.z - mm1.z) * (gg1.z * rsqrtf(vv1.z + BN_EPS_)) + be1.z, 0.f);
    float o7 = fmaxf((di * a7 + bb1.w - mm1.w) * (gg1.w * rsqrtf(vv1.w + BN_EPS_)) + be1.w, 0.f);

    if (LAST) {
        float4 w30 = ((const float4*)W3)[fb], w31 = ((const float4*)W3)[fb + 1];
        float p = o0 * w30.x + o1 * w30.y + o2 * w30.z + o3 * w30.w +
                  o4 * w31.x + o5 * w31.y + o6 * w31.z + o7 * w31.w;
        // p is already uniform across es (a-values were es-reduced above);
        // reduce ONLY over the 4 fg lanes (bits 0-1).  [round-8 bug: an extra
        // es "reduce" here multiplied p by 16]
        p += __shfl_xor(p, 1, 64);
        p += __shfl_xor(p, 2, 64);
        if (l == 0) {
            if (P == 0) hs3[i] = p;
            else        hs3[i] = (hs3[i] + p) * di;
        }
    } else {
        if (es == 0) {
            uint4 pk;
            pk.x = (unsigned)f2bf(o0) | ((unsigned)f2bf(o1) << 16);
            pk.y = (unsigned)f2bf(o2) | ((unsigned)f2bf(o3) << 16);
            pk.z = (unsigned)f2bf(o4) | ((unsigned)f2bf(o5) << 16);
            pk.w = (unsigned)f2bf(o6) | ((unsigned)f2bf(o7) << 16);
            ((uint4*)y)[(long)i * 8 + P * 4 + fg] = pk;
        }
    }
}

// --------- MFMA GEMM: hs subtables (bf16) = (X @ W) * dinv[row] ------------
// Subtable layout: feature f=16c+m of node lives at
//   hs[ ((f>>5)*SUB + node)*32 + (f&31) ]
// Node N_NODES is a ZERO row in both subtables (gather sentinel target).
template<int K, bool BF16IN>
__global__ __launch_bounds__(256) void gemm_bf16(const void* __restrict__ Xv,
                                                 const float* __restrict__ W,   // [K][64]
                                                 const float* __restrict__ dinv,
                                                 ushort* __restrict__ hs) {
    constexpr int KP = K + 8;
    __shared__ ushort A_lds[64][KP];
    __shared__ ushort Wt_lds[64][KP];
    int t = threadIdx.x;
    long row0 = (long)blockIdx.x * 64;

    for (int i = t; i < K * 16; i += 256) {
        float4 w4 = ((const float4*)W)[i];
        int k = i >> 4, n = (i & 15) * 4;
        Wt_lds[n + 0][k] = f2bf(w4.x);
        Wt_lds[n + 1][k] = f2bf(w4.y);
        Wt_lds[n + 2][k] = f2bf(w4.z);
        Wt_lds[n + 3][k] = f2bf(w4.w);
    }
    if (BF16IN) {
        constexpr int K2 = K / 2;
        const unsigned* X = (const unsigned*)Xv;
        for (int i = t; i < 64 * K2; i += 256) {
            int r = i / K2, c = i % K2;
            unsigned val = 0;
            long row = row0 + r;
            if (row < N_NODES) val = X[row * K2 + c];
            *(unsigned*)&A_lds[r][c * 2] = val;
        }
    } else {
        constexpr int K4 = K / 4;
        const float* X = (const float*)Xv;
        for (int i = t; i < 64 * K4; i += 256) {
            int r = i / K4, c = i % K4;
            float4 val = make_float4(0.f, 0.f, 0.f, 0.f);
            long row = row0 + r;
            if (row < N_NODES) val = ((const float4*)X)[row * K4 + c];
            int cb = c * 4;
            A_lds[r][cb + 0] = f2bf(val.x);
            A_lds[r][cb + 1] = f2bf(val.y);
            A_lds[r][cb + 2] = f2bf(val.z);
            A_lds[r][cb + 3] = f2bf(val.w);
        }
    }
    __syncthreads();

    int w = t >> 6, l = t & 63;
    int m = l & 15, quad = l >> 4;
    f32x4 acc[4];
#pragma unroll
    for (int c = 0; c < 4; c++) acc[c] = (f32x4){0.f, 0.f, 0.f, 0.f};

#pragma unroll
    for (int ch = 0; ch < K / 32; ch++) {
        short8 a = *(const short8*)&A_lds[16 * w + m][32 * ch + 8 * quad];
#pragma unroll
        for (int c = 0; c < 4; c++) {
            short8 b = *(const short8*)&Wt_lds[16 * c + m][32 * ch + 8 * quad];
            acc[c] = __builtin_amdgcn_mfma_f32_16x16x32_bf16(a, b, acc[c], 0, 0, 0);
        }
    }

#pragma unroll
    for (int r = 0; r < 4; r++) {
        long node = row0 + 16 * w + quad * 4 + r;
        if (node <= N_NODES) {                       // include zero row N
            float dv = (node < N_NODES) ? dinv[node] : 0.f;
#pragma unroll
            for (int c = 0; c < 4; c++)
                hs[((long)(c >> 1) * SUB + node) * 32 + (c & 1) * 16 + m] = f2bf(acc[c][r] * dv);
        }
    }
}

// ---------------- layer-3 pull + sigmoid (padded rows, hs3[N]=0) -----------
__global__ __launch_bounds__(256) void gather3(const int* __restrict__ row_ptr,
                                               const int* __restrict__ csr_src,
                                               const float* __restrict__ hs3,
                                               const float* __restrict__ dinv,
                                               const float* __restrict__ b3,
                                               float* __restrict__ out, int n) {
    int i = blockIdx.x * 256 + threadIdx.x;
    if (i >= n) return;
    int beg = row_ptr[i], end = row_ptr[i + 1];
    float s0 = hs3[i], s1 = 0.f, s2 = 0.f, s3 = 0.f;
    float s4 = 0.f, s5 = 0.f, s6 = 0.f, s7 = 0.f;
    for (int k = beg; k + 8 <= end; k += 8) {
        s0 += hs3[csr_src[k]];
        s1 += hs3[csr_src[k + 1]];
        s2 += hs3[csr_src[k + 2]];
        s3 += hs3[csr_src[k + 3]];
        s4 += hs3[csr_src[k + 4]];
        s5 += hs3[csr_src[k + 5]];
        s6 += hs3[csr_src[k + 6]];
        s7 += hs3[csr_src[k + 7]];
    }
    float z = dinv[i] * (((s0 + s1) + (s2 + s3)) + ((s4 + s5) + (s6 + s7))) + b3[0];
    out[i] = 1.f / (1.f + expf(-z));
}

extern "C" void kernel_launch(void* const* d_in, const int* in_sizes, int n_in,
                              void* d_out, int out_size, void* d_ws, size_t ws_size,
                              hipStream_t stream) {
    const int N = N_NODES;
    const int E = E_EDGES;

    const float* x   = (const float*)d_in[0];
    const int*   ei  = (const int*)d_in[1];   // [2, E]: row0=src, row1=dst
    const float* W1  = (const float*)d_in[2];
    const float* b1  = (const float*)d_in[3];
    const float* W2  = (const float*)d_in[4];
    const float* b2  = (const float*)d_in[5];
    const float* W3  = (const float*)d_in[6];
    const float* b3  = (const float*)d_in[7];
    const float* g1  = (const float*)d_in[8];
    const float* bt1 = (const float*)d_in[9];
    const float* m1  = (const float*)d_in[10];
    const float* v1  = (const float*)d_in[11];
    const float* g2  = (const float*)d_in[12];
    const float* bt2 = (const float*)d_in[13];
    const float* m2  = (const float*)d_in[14];
    const float* v2  = (const float*)d_in[15];
    float* out = (float*)d_out;

    // workspace layout (4-byte units)
    int*    wsi          = (int*)d_ws;
    float*  dinv         = (float*)wsi;                       // N
    float*  hs3          = (float*)(wsi + (long)N);           // N+1 (pad 16)
    int*    row_ptr      = wsi + 2L * N + 16;                 // N+1 (pad 16)
    int*    deg          = row_ptr + N + 16;                  // N (pad 16)
    int*    histPB       = deg + N + 16;                      // NBUCK*PB = 97750
    int*    bucket_tot   = histPB + NBUCK * PB;               // 400
    int*    bucket_base  = bucket_tot + 400;                  // NBUCK+1 (pad 402)
    int*    bucket_ptot  = bucket_base + 402;                 // 400
    int*    bucket_pbase = bucket_ptot + 400;                 // 400 (+2 align)
    ushort* hsb          = (ushort*)(bucket_pbase + 402);     // 2 subtables: SUB*32 ints
    unsigned* yb         = (unsigned*)((int*)(void*)hsb + 32L * SUB); // N*32 uints
    int*    csr_src      = (int*)yb + 32L * N;                // padded: up to E+16N
    int*    ebuf         = (int*)(void*)hsb;                  // E ints, aliases hsb (build only)

    // ---- CSR build (bucketed counting sort, padded rows, no global atomics) --
    passA1_hist<<<PB, 512, 0, stream>>>(ei, histPB);
    scan_rows<<<NBUCK, 256, 0, stream>>>(histPB, bucket_tot);
    scan_totals<<<1, 512, 0, stream>>>(bucket_tot, bucket_base, hs3);
    passA2_sorted<<<PB, 512, 0, stream>>>(ei, histPB, bucket_base, ebuf);
    bucket_deg<<<NBUCK, 256, 0, stream>>>(ebuf, bucket_base, deg, dinv, bucket_ptot);
    scan_ptot<<<1, 512, 0, stream>>>(bucket_ptot, bucket_pbase, row_ptr);
    passB_sorted<<<NBUCK, 256, 0, stream>>>(ebuf, bucket_base, bucket_pbase,
                                            deg, row_ptr, csr_src);

    const int GG = (N + 3) / 4;   // one row per wave

    // ---- layer 1: GEMM + 2 feature-split gather passes ----
    gemm_bf16<IN_DIM_, false><<<(N + 63) / 64, 256, 0, stream>>>(x, W1, dinv, hsb);
    gather_pass<false, 0><<<GG, 256, 0, stream>>>(row_ptr, csr_src, hsb, dinv,
                                                  b1, g1, bt1, m1, v1, yb, W3, hs3, N);
    gather_pass<false, 1><<<GG, 256, 0, stream>>>(row_ptr, csr_src, hsb, dinv,
                                                  b1, g1, bt1, m1, v1, yb, W3, hs3, N);
    // ---- layer 2: GEMM + 2 passes (fused gemv3 accumulation into hs3) ----
    gemm_bf16<HID_, true><<<(N + 63) / 64, 256, 0, stream>>>(yb, W2, dinv, hsb);
    gather_pass<true, 0><<<GG, 256, 0, stream>>>(row_ptr, csr_src, hsb, dinv,
                                                 b2, g2, bt2, m2, v2, yb, W3, hs3, N);
    gather_pass<true, 1><<<GG, 256, 0, stream>>>(row_ptr, csr_src, hsb, dinv,
                                                 b2, g2, bt2, m2, v2, yb, W3, hs3, N);
    // ---- layer 3 ----
    gather3<<<(N + 255) / 256, 256, 0, stream>>>(row_ptr, csr_src, hs3, dinv, b3, out, N);
}

// Round 10
// 484.473 us; speedup vs baseline: 1.4786x; 1.0113x over previous
//
#include <hip/hip_runtime.h>
#include <math.h>

#define N_NODES 100000
#define E_EDGES 3200000
#define IN_DIM_ 128
#define HID_ 64
#define BN_EPS_ 1e-5f

#define PB 250          // edge-chunk blocks
#define CHUNK 12800     // E / PB exactly
#define NBUCK 391       // ceil(N / 256): bucket = dst >> 8
#define BMAX 9600       // passB LDS capacity (bucket mean 8184, 15 sigma)
#define SUB (N_NODES + 1)   // rows per feature-subtable (incl zero row)

typedef __attribute__((ext_vector_type(8))) short short8;
typedef __attribute__((ext_vector_type(4))) float f32x4;

__device__ inline ushort f2bf(float f) {
    union { float f; unsigned u; } c; c.f = f;
    unsigned r = c.u + 0x7fff + ((c.u >> 16) & 1);   // RNE
    return (ushort)(r >> 16);
}
__device__ inline float bf_lo(unsigned p) { union { unsigned u; float f; } c; c.u = p << 16; return c.f; }
__device__ inline float bf_hi(unsigned p) { union { unsigned u; float f; } c; c.u = p & 0xffff0000u; return c.f; }

// ---------------- pass A1: per-block bucket histogram ----------------
__global__ __launch_bounds__(512) void passA1_hist(const int* __restrict__ ei,
                                                   int* __restrict__ histPB) {
    __shared__ int hist[NBUCK];
    int t = threadIdx.x, b = blockIdx.x;
    for (int k = t; k < NBUCK; k += 512) hist[k] = 0;
    __syncthreads();
    int e0 = b * CHUNK, e1 = e0 + CHUNK;
    for (int e = e0 + t; e < e1; e += 512) {
        int d = ei[E_EDGES + e];
        atomicAdd(&hist[d >> 8], 1);
    }
    __syncthreads();
    for (int k = t; k < NBUCK; k += 512) histPB[k * PB + b] = hist[k];
}

// ---------------- per-bucket row scan (ebuf addressing) ----------------
__global__ __launch_bounds__(256) void scan_rows(int* __restrict__ histPB,
                                                 int* __restrict__ bucket_tot) {
    __shared__ int wsum[4];
    int k = blockIdx.x, t = threadIdx.x, lane = t & 63, wv = t >> 6;
    int v = (t < PB) ? histPB[k * PB + t] : 0;
    int s = v;
#pragma unroll
    for (int off = 1; off < 64; off <<= 1) {
        int u = __shfl_up(s, off, 64);
        if (lane >= off) s += u;
    }
    if (lane == 63) wsum[wv] = s;
    __syncthreads();
    int wbase = 0;
    for (int w = 0; w < wv; w++) wbase += wsum[w];
    if (t < PB) histPB[k * PB + t] = wbase + s - v;
    if (t == 255) bucket_tot[k] = wbase + s;
}

// ---------------- scan bucket totals -> bucket_base (ebuf) ----------------
__global__ __launch_bounds__(512) void scan_totals(const int* __restrict__ bucket_tot,
                                                   int* __restrict__ bucket_base,
                                                   float* __restrict__ hs3) {
    __shared__ int wsum[8];
    int t = threadIdx.x, lane = t & 63, wv = t >> 6;
    int v = (t < NBUCK) ? bucket_tot[t] : 0;
    int s = v;
#pragma unroll
    for (int off = 1; off < 64; off <<= 1) {
        int u = __shfl_up(s, off, 64);
        if (lane >= off) s += u;
    }
    if (lane == 63) wsum[wv] = s;
    __syncthreads();
    int wbase = 0;
    for (int w = 0; w < wv; w++) wbase += wsum[w];
    if (t < NBUCK) bucket_base[t] = wbase + s - v;
    if (t == 0) {
        bucket_base[NBUCK] = E_EDGES;
        hs3[N_NODES] = 0.f;          // sentinel target for gather3
    }
}

// ---- pass A2: LDS counting sort per chunk -> COALESCED ebuf writes ----
__global__ __launch_bounds__(512) void passA2_sorted(const int* __restrict__ ei,
                                                     const int* __restrict__ histPB,
                                                     const int* __restrict__ bucket_base,
                                                     int* __restrict__ ebuf) {
    __shared__ int sorted[CHUNK];     // 51.2 KB
    __shared__ ushort bid[CHUNK];     // 25.6 KB
    __shared__ int cur[NBUCK];
    __shared__ int lbase[NBUCK];
    int t = threadIdx.x, b = blockIdx.x;
    for (int k = t; k < NBUCK; k += 512) cur[k] = 0;
    __syncthreads();
    int e0 = b * CHUNK;
    for (int e = e0 + t; e < e0 + CHUNK; e += 512)
        atomicAdd(&cur[ei[E_EDGES + e] >> 8], 1);
    __syncthreads();
    if (t < 64) {
        int run = 0;
        for (int c0 = 0; c0 < NBUCK; c0 += 64) {
            int idx = c0 + t;
            int v = (idx < NBUCK) ? cur[idx] : 0;
            int s = v;
#pragma unroll
            for (int off = 1; off < 64; off <<= 1) {
                int u = __shfl_up(s, off, 64);
                if (t >= off) s += u;
            }
            if (idx < NBUCK) lbase[idx] = run + s - v;
            run += __shfl(s, 63, 64);
        }
    }
    __syncthreads();
    for (int k = t; k < NBUCK; k += 512) cur[k] = lbase[k];
    __syncthreads();
    for (int e = e0 + t; e < e0 + CHUNK; e += 512) {
        int s = ei[e];
        int d = ei[E_EDGES + e];
        int k = d >> 8;
        int pos = atomicAdd(&cur[k], 1);
        sorted[pos] = s | ((d & 255) << 17);
        bid[pos] = (ushort)k;
    }
    __syncthreads();
    for (int j = t; j < CHUNK; j += 512) {
        int k = bid[j];
        int dest = bucket_base[k] + histPB[k * PB + b] + (j - lbase[k]);
        ebuf[dest] = sorted[j];
    }
}

// ---- bucket_deg: per-node degree via LDS counting over ebuf (NO global atomics)
__global__ __launch_bounds__(256) void bucket_deg(const int* __restrict__ ebuf,
                                                  const int* __restrict__ bucket_base,
                                                  int* __restrict__ deg,
                                                  float* __restrict__ dinv,
                                                  int* __restrict__ bucket_ptot) {
    __shared__ int hist[256];
    __shared__ int wsum[4];
    int b = blockIdx.x, t = threadIdx.x, lane = t & 63, wv = t >> 6;
    int base = bucket_base[b], end = bucket_base[b + 1];
    hist[t] = 0;
    __syncthreads();
    for (int k = base + t; k < end; k += 256)
        atomicAdd(&hist[ebuf[k] >> 17], 1);
    __syncthreads();
    int node = b * 256 + t;
    int d = hist[t];
    if (node < N_NODES) {
        deg[node] = d;
        dinv[node] = rsqrtf((float)d + 1.0f);
    }
    int pd = (node < N_NODES) ? ((d + 7) & ~7) : 0;
#pragma unroll
    for (int off = 1; off < 64; off <<= 1) pd += __shfl_xor(pd, off, 64);
    if (lane == 0) wsum[wv] = pd;
    __syncthreads();
    if (t == 0) bucket_ptot[b] = wsum[0] + wsum[1] + wsum[2] + wsum[3];
}

// ---------------- scan padded totals -> bucket_pbase ----------------
__global__ __launch_bounds__(512) void scan_ptot(const int* __restrict__ bucket_ptot,
                                                 int* __restrict__ bucket_pbase,
                                                 int* __restrict__ row_ptr) {
    __shared__ int wsum[8];
    int t = threadIdx.x, lane = t & 63, wv = t >> 6;
    int v = (t < NBUCK) ? bucket_ptot[t] : 0;
    int s = v;
#pragma unroll
    for (int off = 1; off < 64; off <<= 1) {
        int u = __shfl_up(s, off, 64);
        if (lane >= off) s += u;
    }
    if (lane == 63) wsum[wv] = s;
    __syncthreads();
    int wbase = 0;
    for (int w = 0; w < wv; w++) wbase += wsum[w];
    if (t < NBUCK) bucket_pbase[t] = wbase + s - v;
    if (t == NBUCK - 1) row_ptr[N_NODES] = wbase + s;
}

// ---- pass B: bucket sort -> PADDED csr (rows padded to x8 with sentinel) ---
__global__ __launch_bounds__(256) void passB_sorted(const int* __restrict__ ebuf,
                                                    const int* __restrict__ bucket_base,
                                                    const int* __restrict__ bucket_pbase,
                                                    const int* __restrict__ deg,
                                                    int* __restrict__ row_ptr,
                                                    int* __restrict__ csr_src) {
    __shared__ int sorted[BMAX];      // 38.4 KB
    __shared__ int ucur[256];
    __shared__ int ubeg[256];
    __shared__ int pbeg[256];
    __shared__ int wsA[4], wsB[4];
    int b = blockIdx.x, t = threadIdx.x, lane = t & 63, wv = t >> 6;
    int base = bucket_base[b], end = bucket_base[b + 1];
    int pbase = bucket_pbase[b];
    int node = b * 256 + t;
    int d = (node < N_NODES) ? deg[node] : 0;
    int pd = (d + 7) & ~7;
    if (node >= N_NODES) pd = 0;
    int sa = d, sb = pd;
#pragma unroll
    for (int off = 1; off < 64; off <<= 1) {
        int ua = __shfl_up(sa, off, 64);
        int ub = __shfl_up(sb, off, 64);
        if (lane >= off) { sa += ua; sb += ub; }
    }
    if (lane == 63) { wsA[wv] = sa; wsB[wv] = sb; }
    __syncthreads();
    int wa = 0, wb = 0;
    for (int w = 0; w < wv; w++) { wa += wsA[w]; wb += wsB[w]; }
    int uex = wa + sa - d, pex = wb + sb - pd;
    ubeg[t] = uex; pbeg[t] = pex; ucur[t] = uex;
    if (node < N_NODES) row_ptr[node] = pbase + pex;
    __syncthreads();
    for (int k = base + t; k < end; k += 256) {
        int pv = ebuf[k];
        int pos = atomicAdd(&ucur[pv >> 17], 1);
        if (pos < BMAX) sorted[pos] = pv;    // overflow ~impossible (15 sigma)
    }
    __syncthreads();
    // write out padded rows: real entries then sentinel (zero-row) padding
    for (int r = wv; r < 256; r += 4) {
        int nd = b * 256 + r;
        int d2 = (nd < N_NODES) ? deg[nd] : 0;
        int pd2 = (nd < N_NODES) ? ((d2 + 7) & ~7) : 0;
        int ub = ubeg[r], pb = pbeg[r];
        for (int c = lane; c < pd2; c += 64)
            csr_src[pbase + pb + c] = (c < d2) ? (sorted[ub + c] & 0x1FFFF) : N_NODES;
    }
}

// ---- pull-gather (single pass): 8 es x 8 fg, 4-deep gather pipeline -------
// fg lane reads uint4 = features [fg*8, fg*8+8): fg 0-3 hit subtable 0,
// fg 4-7 hit subtable 1 (64 B rows each). Rows padded to x8 with sentinel
// N_NODES (zero row in both subtables) -> branch/clamp-free inner loop with
// 4 index loads + 4 row gathers in flight (round-1's proven ILP).
template<bool LAST>
__global__ __launch_bounds__(256) void gather_full(const int* __restrict__ row_ptr,
                                                   const int* __restrict__ csr_src,
                                                   const ushort* __restrict__ hs,
                                                   const float* __restrict__ dinv,
                                                   const float* __restrict__ b,
                                                   const float* __restrict__ g,
                                                   const float* __restrict__ beta,
                                                   const float* __restrict__ m,
                                                   const float* __restrict__ v,
                                                   unsigned* __restrict__ y,
                                                   const float* __restrict__ W3,
                                                   float* __restrict__ hs3, int n) {
    int i = (blockIdx.x * 256 + threadIdx.x) >> 6;
    if (i >= n) return;
    int l = threadIdx.x & 63;
    int es = l >> 3, fg = l & 7;

    // lane's subtable pointer: subtable fg>>2, quarter-row fg&3
    const uint4* Tq = (const uint4*)hs + (long)(fg >> 2) * SUB * 4 + (fg & 3);

    float a0 = 0.f, a1 = 0.f, a2 = 0.f, a3 = 0.f;
    float a4 = 0.f, a5 = 0.f, a6 = 0.f, a7 = 0.f;

    if (es == 0) {   // self-loop
        uint4 p = Tq[(unsigned)i * 4];
        a0 += bf_lo(p.x); a1 += bf_hi(p.x);
        a2 += bf_lo(p.y); a3 += bf_hi(p.y);
        a4 += bf_lo(p.z); a5 += bf_hi(p.z);
        a6 += bf_lo(p.w); a7 += bf_hi(p.w);
    }

    int pbeg = row_ptr[i], pend = row_ptr[i + 1];
    const int* cs = csr_src + pbeg + es;
    int nb8 = (pend - pbeg) >> 3;
    int full = nb8 >> 2;
    for (int t = 0; t < full; t++) {
        int s0 = cs[0], s1 = cs[8], s2 = cs[16], s3 = cs[24];
        cs += 32;
        uint4 p0 = Tq[(unsigned)s0 * 4];
        uint4 p1 = Tq[(unsigned)s1 * 4];
        uint4 p2 = Tq[(unsigned)s2 * 4];
        uint4 p3 = Tq[(unsigned)s3 * 4];
        a0 += bf_lo(p0.x) + bf_lo(p1.x); a1 += bf_hi(p0.x) + bf_hi(p1.x);
        a2 += bf_lo(p0.y) + bf_lo(p1.y); a3 += bf_hi(p0.y) + bf_hi(p1.y);
        a4 += bf_lo(p0.z) + bf_lo(p1.z); a5 += bf_hi(p0.z) + bf_hi(p1.z);
        a6 += bf_lo(p0.w) + bf_lo(p1.w); a7 += bf_hi(p0.w) + bf_hi(p1.w);
        a0 += bf_lo(p2.x) + bf_lo(p3.x); a1 += bf_hi(p2.x) + bf_hi(p3.x);
        a2 += bf_lo(p2.y) + bf_lo(p3.y); a3 += bf_hi(p2.y) + bf_hi(p3.y);
        a4 += bf_lo(p2.z) + bf_lo(p3.z); a5 += bf_hi(p2.z) + bf_hi(p3.z);
        a6 += bf_lo(p2.w) + bf_lo(p3.w); a7 += bf_hi(p2.w) + bf_hi(p3.w);
    }
    for (int rem = nb8 & 3; rem > 0; rem--) {
        int s = cs[0];
        cs += 8;
        uint4 p = Tq[(unsigned)s * 4];
        a0 += bf_lo(p.x); a1 += bf_hi(p.x);
        a2 += bf_lo(p.y); a3 += bf_hi(p.y);
        a4 += bf_lo(p.z); a5 += bf_hi(p.z);
        a6 += bf_lo(p.w); a7 += bf_hi(p.w);
    }

    // reduce over the 8 es slots (lanes sharing fg)
#pragma unroll
    for (int off = 8; off < 64; off <<= 1) {
        a0 += __shfl_xor(a0, off, 64);
        a1 += __shfl_xor(a1, off, 64);
        a2 += __shfl_xor(a2, off, 64);
        a3 += __shfl_xor(a3, off, 64);
        a4 += __shfl_xor(a4, off, 64);
        a5 += __shfl_xor(a5, off, 64);
        a6 += __shfl_xor(a6, off, 64);
        a7 += __shfl_xor(a7, off, 64);
    }

    float4 bb0 = ((const float4*)b)[fg * 2],    bb1 = ((const float4*)b)[fg * 2 + 1];
    float4 gg0 = ((const float4*)g)[fg * 2],    gg1 = ((const float4*)g)[fg * 2 + 1];
    float4 be0 = ((const float4*)beta)[fg * 2], be1 = ((const float4*)beta)[fg * 2 + 1];
    float4 mm0 = ((const float4*)m)[fg * 2],    mm1 = ((const float4*)m)[fg * 2 + 1];
    float4 vv0 = ((const float4*)v)[fg * 2],    vv1 = ((const float4*)v)[fg * 2 + 1];
    float di = dinv[i];
    float o0 = fmaxf((di * a0 + bb0.x - mm0.x) * (gg0.x * rsqrtf(vv0.x + BN_EPS_)) + be0.x, 0.f);
    float o1 = fmaxf((di * a1 + bb0.y - mm0.y) * (gg0.y * rsqrtf(vv0.y + BN_EPS_)) + be0.y, 0.f);
    float o2 = fmaxf((di * a2 + bb0.z - mm0.z) * (gg0.z * rsqrtf(vv0.z + BN_EPS_)) + be0.z, 0.f);
    float o3 = fmaxf((di * a3 + bb0.w - mm0.w) * (gg0.w * rsqrtf(vv0.w + BN_EPS_)) + be0.w, 0.f);
    float o4 = fmaxf((di * a4 + bb1.x - mm1.x) * (gg1.x * rsqrtf(vv1.x + BN_EPS_)) + be1.x, 0.f);
    float o5 = fmaxf((di * a5 + bb1.y - mm1.y) * (gg1.y * rsqrtf(vv1.y + BN_EPS_)) + be1.y, 0.f);
    float o6 = fmaxf((di * a6 + bb1.z - mm1.z) * (gg1.z * rsqrtf(vv1.z + BN_EPS_)) + be1.z, 0.f);
    float o7 = fmaxf((di * a7 + bb1.w - mm1.w) * (gg1.w * rsqrtf(vv1.w + BN_EPS_)) + be1.w, 0.f);

    if (LAST) {
        float4 w30 = ((const float4*)W3)[fg * 2], w31 = ((const float4*)W3)[fg * 2 + 1];
        float p = o0 * w30.x + o1 * w30.y + o2 * w30.z + o3 * w30.w +
                  o4 * w31.x + o5 * w31.y + o6 * w31.z + o7 * w31.w;
        // p is es-uniform; reduce over the 8 fg lanes only
#pragma unroll
        for (int off = 1; off < 8; off <<= 1)
            p += __shfl_xor(p, off, 64);
        if (l == 0) hs3[i] = p * di;
    } else {
        if (es == 0) {
            uint4 pk;
            pk.x = (unsigned)f2bf(o0) | ((unsigned)f2bf(o1) << 16);
            pk.y = (unsigned)f2bf(o2) | ((unsigned)f2bf(o3) << 16);
            pk.z = (unsigned)f2bf(o4) | ((unsigned)f2bf(o5) << 16);
            pk.w = (unsigned)f2bf(o6) | ((unsigned)f2bf(o7) << 16);
            ((uint4*)y)[(long)i * 8 + fg] = pk;
        }
    }
}

// --------- MFMA GEMM: hs subtables (bf16) = (X @ W) * dinv[row] ------------
// Subtable layout: feature f=16c+m of node lives at
//   hs[ ((f>>5)*SUB + node)*32 + (f&31) ]
// Node N_NODES is a ZERO row in both subtables (gather sentinel target).
template<int K, bool BF16IN>
__global__ __launch_bounds__(256) void gemm_bf16(const void* __restrict__ Xv,
                                                 const float* __restrict__ W,   // [K][64]
                                                 const float* __restrict__ dinv,
                                                 ushort* __restrict__ hs) {
    constexpr int KP = K + 8;
    __shared__ ushort A_lds[64][KP];
    __shared__ ushort Wt_lds[64][KP];
    int t = threadIdx.x;
    long row0 = (long)blockIdx.x * 64;

    for (int i = t; i < K * 16; i += 256) {
        float4 w4 = ((const float4*)W)[i];
        int k = i >> 4, n = (i & 15) * 4;
        Wt_lds[n + 0][k] = f2bf(w4.x);
        Wt_lds[n + 1][k] = f2bf(w4.y);
        Wt_lds[n + 2][k] = f2bf(w4.z);
        Wt_lds[n + 3][k] = f2bf(w4.w);
    }
    if (BF16IN) {
        constexpr int K2 = K / 2;
        const unsigned* X = (const unsigned*)Xv;
        for (int i = t; i < 64 * K2; i += 256) {
            int r = i / K2, c = i % K2;
            unsigned val = 0;
            long row = row0 + r;
            if (row < N_NODES) val = X[row * K2 + c];
            *(unsigned*)&A_lds[r][c * 2] = val;
        }
    } else {
        constexpr int K4 = K / 4;
        const float* X = (const float*)Xv;
        for (int i = t; i < 64 * K4; i += 256) {
            int r = i / K4, c = i % K4;
            float4 val = make_float4(0.f, 0.f, 0.f, 0.f);
            long row = row0 + r;
            if (row < N_NODES) val = ((const float4*)X)[row * K4 + c];
            int cb = c * 4;
            A_lds[r][cb + 0] = f2bf(val.x);
            A_lds[r][cb + 1] = f2bf(val.y);
            A_lds[r][cb + 2] = f2bf(val.z);
            A_lds[r][cb + 3] = f2bf(val.w);
        }
    }
    __syncthreads();

    int w = t >> 6, l = t & 63;
    int m = l & 15, quad = l >> 4;
    f32x4 acc[4];
#pragma unroll
    for (int c = 0; c < 4; c++) acc[c] = (f32x4){0.f, 0.f, 0.f, 0.f};

#pragma unroll
    for (int ch = 0; ch < K / 32; ch++) {
        short8 a = *(const short8*)&A_lds[16 * w + m][32 * ch + 8 * quad];
#pragma unroll
        for (int c = 0; c < 4; c++) {
            short8 b = *(const short8*)&Wt_lds[16 * c + m][32 * ch + 8 * quad];
            acc[c] = __builtin_amdgcn_mfma_f32_16x16x32_bf16(a, b, acc[c], 0, 0, 0);
        }
    }

#pragma unroll
    for (int r = 0; r < 4; r++) {
        long node = row0 + 16 * w + quad * 4 + r;
        if (node <= N_NODES) {                       // include zero row N
            float dv = (node < N_NODES) ? dinv[node] : 0.f;
#pragma unroll
            for (int c = 0; c < 4; c++)
                hs[((long)(c >> 1) * SUB + node) * 32 + (c & 1) * 16 + m] = f2bf(acc[c][r] * dv);
        }
    }
}

// ---------------- layer-3 pull + sigmoid (padded rows, hs3[N]=0) -----------
__global__ __launch_bounds__(256) void gather3(const int* __restrict__ row_ptr,
                                               const int* __restrict__ csr_src,
                                               const float* __restrict__ hs3,
                                               const float* __restrict__ dinv,
                                               const float* __restrict__ b3,
                                               float* __restrict__ out, int n) {
    int i = blockIdx.x * 256 + threadIdx.x;
    if (i >= n) return;
    int beg = row_ptr[i], end = row_ptr[i + 1];
    float s0 = hs3[i], s1 = 0.f, s2 = 0.f, s3 = 0.f;
    float s4 = 0.f, s5 = 0.f, s6 = 0.f, s7 = 0.f;
    for (int k = beg; k + 8 <= end; k += 8) {
        s0 += hs3[csr_src[k]];
        s1 += hs3[csr_src[k + 1]];
        s2 += hs3[csr_src[k + 2]];
        s3 += hs3[csr_src[k + 3]];
        s4 += hs3[csr_src[k + 4]];
        s5 += hs3[csr_src[k + 5]];
        s6 += hs3[csr_src[k + 6]];
        s7 += hs3[csr_src[k + 7]];
    }
    float z = dinv[i] * (((s0 + s1) + (s2 + s3)) + ((s4 + s5) + (s6 + s7))) + b3[0];
    out[i] = 1.f / (1.f + expf(-z));
}

extern "C" void kernel_launch(void* const* d_in, const int* in_sizes, int n_in,
                              void* d_out, int out_size, void* d_ws, size_t ws_size,
                              hipStream_t stream) {
    const int N = N_NODES;
    const int E = E_EDGES;

    const float* x   = (const float*)d_in[0];
    const int*   ei  = (const int*)d_in[1];   // [2, E]: row0=src, row1=dst
    const float* W1  = (const float*)d_in[2];
    const float* b1  = (const float*)d_in[3];
    const float* W2  = (const float*)d_in[4];
    const float* b2  = (const float*)d_in[5];
    const float* W3  = (const float*)d_in[6];
    const float* b3  = (const float*)d_in[7];
    const float* g1  = (const float*)d_in[8];
    const float* bt1 = (const float*)d_in[9];
    const float* m1  = (const float*)d_in[10];
    const float* v1  = (const float*)d_in[11];
    const float* g2  = (const float*)d_in[12];
    const float* bt2 = (const float*)d_in[13];
    const float* m2  = (const float*)d_in[14];
    const float* v2  = (const float*)d_in[15];
    float* out = (float*)d_out;

    // workspace layout (4-byte units)
    int*    wsi          = (int*)d_ws;
    float*  dinv         = (float*)wsi;                       // N
    float*  hs3          = (float*)(wsi + (long)N);           // N+1 (pad 16)
    int*    row_ptr      = wsi + 2L * N + 16;                 // N+1 (pad 16)
    int*    deg          = row_ptr + N + 16;                  // N (pad 16)
    int*    histPB       = deg + N + 16;                      // NBUCK*PB = 97750
    int*    bucket_tot   = histPB + NBUCK * PB;               // 400
    int*    bucket_base  = bucket_tot + 400;                  // NBUCK+1 (pad 402)
    int*    bucket_ptot  = bucket_base + 402;                 // 400
    int*    bucket_pbase = bucket_ptot + 400;                 // 400 (+2 align)
    ushort* hsb          = (ushort*)(bucket_pbase + 402);     // 2 subtables: SUB*32 ints
    unsigned* yb         = (unsigned*)((int*)(void*)hsb + 32L * SUB); // N*32 uints
    int*    csr_src      = (int*)yb + 32L * N;                // padded: up to E+8N
    int*    ebuf         = (int*)(void*)hsb;                  // E ints, aliases hsb (build only)

    // ---- CSR build (bucketed counting sort, padded rows, no global atomics) --
    passA1_hist<<<PB, 512, 0, stream>>>(ei, histPB);
    scan_rows<<<NBUCK, 256, 0, stream>>>(histPB, bucket_tot);
    scan_totals<<<1, 512, 0, stream>>>(bucket_tot, bucket_base, hs3);
    passA2_sorted<<<PB, 512, 0, stream>>>(ei, histPB, bucket_base, ebuf);
    bucket_deg<<<NBUCK, 256, 0, stream>>>(ebuf, bucket_base, deg, dinv, bucket_ptot);
    scan_ptot<<<1, 512, 0, stream>>>(bucket_ptot, bucket_pbase, row_ptr);
    passB_sorted<<<NBUCK, 256, 0, stream>>>(ebuf, bucket_base, bucket_pbase,
                                            deg, row_ptr, csr_src);

    const int GG = (N + 3) / 4;   // one row per wave

    // ---- layer 1 ----
    gemm_bf16<IN_DIM_, false><<<(N + 63) / 64, 256, 0, stream>>>(x, W1, dinv, hsb);
    gather_full<false><<<GG, 256, 0, stream>>>(row_ptr, csr_src, hsb, dinv,
                                               b1, g1, bt1, m1, v1, yb, W3, hs3, N);
    // ---- layer 2 (+ fused gemv3) ----
    gemm_bf16<HID_, true><<<(N + 63) / 64, 256, 0, stream>>>(yb, W2, dinv, hsb);
    gather_full<true><<<GG, 256, 0, stream>>>(row_ptr, csr_src, hsb, dinv,
                                              b2, g2, bt2, m2, v2, yb, W3, hs3, N);
    // ---- layer 3 ----
    gather3<<<(N + 255) / 256, 256, 0, stream>>>(row_ptr, csr_src, hs3, dinv, b3, out, N);
}

// Round 11
// 416.359 us; speedup vs baseline: 1.7205x; 1.1636x over previous
//
#include <hip/hip_runtime.h>
#include <math.h>

#define N_NODES 100000
#define E_EDGES 3200000
#define IN_DIM_ 128
#define HID_ 64
#define BN_EPS_ 1e-5f

#define PB 250          // edge-chunk blocks
#define CHUNK 12800     // E / PB exactly
#define NBUCK 391       // ceil(N / 256): bucket = dst >> 8
#define BMAX 9600       // passB LDS capacity (bucket mean 8184, 15 sigma)
#define SUB (N_NODES + 1)   // hs rows incl zero row

typedef __attribute__((ext_vector_type(8))) short short8;
typedef __attribute__((ext_vector_type(4))) float f32x4;

__device__ inline ushort f2bf(float f) {
    union { float f; unsigned u; } c; c.f = f;
    unsigned r = c.u + 0x7fff + ((c.u >> 16) & 1);   // RNE
    return (ushort)(r >> 16);
}
__device__ inline float bf_lo(unsigned p) { union { unsigned u; float f; } c; c.u = p << 16; return c.f; }
__device__ inline float bf_hi(unsigned p) { union { unsigned u; float f; } c; c.u = p & 0xffff0000u; return c.f; }

// ---------------- pass A1: per-block bucket histogram ----------------
__global__ __launch_bounds__(512) void passA1_hist(const int* __restrict__ ei,
                                                   int* __restrict__ histPB) {
    __shared__ int hist[NBUCK];
    int t = threadIdx.x, b = blockIdx.x;
    for (int k = t; k < NBUCK; k += 512) hist[k] = 0;
    __syncthreads();
    int e0 = b * CHUNK, e1 = e0 + CHUNK;
    for (int e = e0 + t; e < e1; e += 512) {
        int d = ei[E_EDGES + e];
        atomicAdd(&hist[d >> 8], 1);
    }
    __syncthreads();
    for (int k = t; k < NBUCK; k += 512) histPB[k * PB + b] = hist[k];
}

// ---------------- per-bucket row scan (ebuf addressing) ----------------
__global__ __launch_bounds__(256) void scan_rows(int* __restrict__ histPB,
                                                 int* __restrict__ bucket_tot) {
    __shared__ int wsum[4];
    int k = blockIdx.x, t = threadIdx.x, lane = t & 63, wv = t >> 6;
    int v = (t < PB) ? histPB[k * PB + t] : 0;
    int s = v;
#pragma unroll
    for (int off = 1; off < 64; off <<= 1) {
        int u = __shfl_up(s, off, 64);
        if (lane >= off) s += u;
    }
    if (lane == 63) wsum[wv] = s;
    __syncthreads();
    int wbase = 0;
    for (int w = 0; w < wv; w++) wbase += wsum[w];
    if (t < PB) histPB[k * PB + t] = wbase + s - v;
    if (t == 255) bucket_tot[k] = wbase + s;
}

// ---------------- scan bucket totals -> bucket_base (ebuf) ----------------
__global__ __launch_bounds__(512) void scan_totals(const int* __restrict__ bucket_tot,
                                                   int* __restrict__ bucket_base,
                                                   float* __restrict__ hs3) {
    __shared__ int wsum[8];
    int t = threadIdx.x, lane = t & 63, wv = t >> 6;
    int v = (t < NBUCK) ? bucket_tot[t] : 0;
    int s = v;
#pragma unroll
    for (int off = 1; off < 64; off <<= 1) {
        int u = __shfl_up(s, off, 64);
        if (lane >= off) s += u;
    }
    if (lane == 63) wsum[wv] = s;
    __syncthreads();
    int wbase = 0;
    for (int w = 0; w < wv; w++) wbase += wsum[w];
    if (t < NBUCK) bucket_base[t] = wbase + s - v;
    if (t == 0) {
        bucket_base[NBUCK] = E_EDGES;
        hs3[N_NODES] = 0.f;          // sentinel target for gather3
    }
}

// ---- pass A2: LDS counting sort per chunk -> COALESCED ebuf writes ----
__global__ __launch_bounds__(512) void passA2_sorted(const int* __restrict__ ei,
                                                     const int* __restrict__ histPB,
                                                     const int* __restrict__ bucket_base,
                                                     int* __restrict__ ebuf) {
    __shared__ int sorted[CHUNK];     // 51.2 KB
    __shared__ ushort bid[CHUNK];     // 25.6 KB
    __shared__ int cur[NBUCK];
    __shared__ int lbase[NBUCK];
    int t = threadIdx.x, b = blockIdx.x;
    for (int k = t; k < NBUCK; k += 512) cur[k] = 0;
    __syncthreads();
    int e0 = b * CHUNK;
    for (int e = e0 + t; e < e0 + CHUNK; e += 512)
        atomicAdd(&cur[ei[E_EDGES + e] >> 8], 1);
    __syncthreads();
    if (t < 64) {
        int run = 0;
        for (int c0 = 0; c0 < NBUCK; c0 += 64) {
            int idx = c0 + t;
            int v = (idx < NBUCK) ? cur[idx] : 0;
            int s = v;
#pragma unroll
            for (int off = 1; off < 64; off <<= 1) {
                int u = __shfl_up(s, off, 64);
                if (t >= off) s += u;
            }
            if (idx < NBUCK) lbase[idx] = run + s - v;
            run += __shfl(s, 63, 64);
        }
    }
    __syncthreads();
    for (int k = t; k < NBUCK; k += 512) cur[k] = lbase[k];
    __syncthreads();
    for (int e = e0 + t; e < e0 + CHUNK; e += 512) {
        int s = ei[e];
        int d = ei[E_EDGES + e];
        int k = d >> 8;
        int pos = atomicAdd(&cur[k], 1);
        sorted[pos] = s | ((d & 255) << 17);
        bid[pos] = (ushort)k;
    }
    __syncthreads();
    for (int j = t; j < CHUNK; j += 512) {
        int k = bid[j];
        int dest = bucket_base[k] + histPB[k * PB + b] + (j - lbase[k]);
        ebuf[dest] = sorted[j];
    }
}

// ---- bucket_deg: per-node degree via LDS counting over ebuf (NO global atomics)
__global__ __launch_bounds__(256) void bucket_deg(const int* __restrict__ ebuf,
                                                  const int* __restrict__ bucket_base,
                                                  int* __restrict__ deg,
                                                  float* __restrict__ dinv,
                                                  int* __restrict__ bucket_ptot) {
    __shared__ int hist[256];
    __shared__ int wsum[4];
    int b = blockIdx.x, t = threadIdx.x, lane = t & 63, wv = t >> 6;
    int base = bucket_base[b], end = bucket_base[b + 1];
    hist[t] = 0;
    __syncthreads();
    for (int k = base + t; k < end; k += 256)
        atomicAdd(&hist[ebuf[k] >> 17], 1);
    __syncthreads();
    int node = b * 256 + t;
    int d = hist[t];
    if (node < N_NODES) {
        deg[node] = d;
        dinv[node] = rsqrtf((float)d + 1.0f);
    }
    int pd = (node < N_NODES) ? ((d + 7) & ~7) : 0;
#pragma unroll
    for (int off = 1; off < 64; off <<= 1) pd += __shfl_xor(pd, off, 64);
    if (lane == 0) wsum[wv] = pd;
    __syncthreads();
    if (t == 0) bucket_ptot[b] = wsum[0] + wsum[1] + wsum[2] + wsum[3];
}

// ---------------- scan padded totals -> bucket_pbase ----------------
__global__ __launch_bounds__(512) void scan_ptot(const int* __restrict__ bucket_ptot,
                                                 int* __restrict__ bucket_pbase,
                                                 int* __restrict__ row_ptr) {
    __shared__ int wsum[8];
    int t = threadIdx.x, lane = t & 63, wv = t >> 6;
    int v = (t < NBUCK) ? bucket_ptot[t] : 0;
    int s = v;
#pragma unroll
    for (int off = 1; off < 64; off <<= 1) {
        int u = __shfl_up(s, off, 64);
        if (lane >= off) s += u;
    }
    if (lane == 63) wsum[wv] = s;
    __syncthreads();
    int wbase = 0;
    for (int w = 0; w < wv; w++) wbase += wsum[w];
    if (t < NBUCK) bucket_pbase[t] = wbase + s - v;
    if (t == NBUCK - 1) row_ptr[N_NODES] = wbase + s;
}

// ---- pass B: bucket sort -> PADDED csr (rows padded to x8 with sentinel) ---
__global__ __launch_bounds__(256) void passB_sorted(const int* __restrict__ ebuf,
                                                    const int* __restrict__ bucket_base,
                                                    const int* __restrict__ bucket_pbase,
                                                    const int* __restrict__ deg,
                                                    int* __restrict__ row_ptr,
                                                    int* __restrict__ csr_src) {
    __shared__ int sorted[BMAX];      // 38.4 KB
    __shared__ int ucur[256];
    __shared__ int ubeg[256];
    __shared__ int pbeg[256];
    __shared__ int wsA[4], wsB[4];
    int b = blockIdx.x, t = threadIdx.x, lane = t & 63, wv = t >> 6;
    int base = bucket_base[b], end = bucket_base[b + 1];
    int pbase = bucket_pbase[b];
    int node = b * 256 + t;
    int d = (node < N_NODES) ? deg[node] : 0;
    int pd = (d + 7) & ~7;
    if (node >= N_NODES) pd = 0;
    int sa = d, sb = pd;
#pragma unroll
    for (int off = 1; off < 64; off <<= 1) {
        int ua = __shfl_up(sa, off, 64);
        int ub = __shfl_up(sb, off, 64);
        if (lane >= off) { sa += ua; sb += ub; }
    }
    if (lane == 63) { wsA[wv] = sa; wsB[wv] = sb; }
    __syncthreads();
    int wa = 0, wb = 0;
    for (int w = 0; w < wv; w++) { wa += wsA[w]; wb += wsB[w]; }
    int uex = wa + sa - d, pex = wb + sb - pd;
    ubeg[t] = uex; pbeg[t] = pex; ucur[t] = uex;
    if (node < N_NODES) row_ptr[node] = pbase + pex;
    __syncthreads();
    for (int k = base + t; k < end; k += 256) {
        int pv = ebuf[k];
        int pos = atomicAdd(&ucur[pv >> 17], 1);
        if (pos < BMAX) sorted[pos] = pv;    // overflow ~impossible (15 sigma)
    }
    __syncthreads();
    // write out padded rows: real entries then sentinel (zero-row) padding
    for (int r = wv; r < 256; r += 4) {
        int nd = b * 256 + r;
        int d2 = (nd < N_NODES) ? deg[nd] : 0;
        int pd2 = (nd < N_NODES) ? ((d2 + 7) & ~7) : 0;
        int ub = ubeg[r], pb = pbeg[r];
        for (int c = lane; c < pd2; c += 64)
            csr_src[pbase + pb + c] = (c < d2) ? (sorted[ub + c] & 0x1FFFF) : N_NODES;
    }
}

// ---- pull-gather: 8 es x 8 fg, CONTIGUOUS 128-B rows, 4-deep pipeline -----
// hs row = 64 bf16 = 128 B contiguous (one HBM fill line -> no split-row
// overfetch; round-10 measured 1.47x FETCH for 64-B split rows). fg lane
// reads uint4 #fg of the row = features [fg*8, fg*8+8). Rows padded to x8
// with sentinel N_NODES (zero row) -> branch/clamp-free inner loop.
template<bool LAST>
__global__ __launch_bounds__(256) void gather_full(const int* __restrict__ row_ptr,
                                                   const int* __restrict__ csr_src,
                                                   const ushort* __restrict__ hs,
                                                   const float* __restrict__ dinv,
                                                   const float* __restrict__ b,
                                                   const float* __restrict__ g,
                                                   const float* __restrict__ beta,
                                                   const float* __restrict__ m,
                                                   const float* __restrict__ v,
                                                   unsigned* __restrict__ y,
                                                   const float* __restrict__ W3,
                                                   float* __restrict__ hs3, int n) {
    int i = (blockIdx.x * 256 + threadIdx.x) >> 6;
    if (i >= n) return;
    int l = threadIdx.x & 63;
    int es = l >> 3, fg = l & 7;

    const uint4* Tq = (const uint4*)hs + fg;   // row stride = 8 uint4

    float a0 = 0.f, a1 = 0.f, a2 = 0.f, a3 = 0.f;
    float a4 = 0.f, a5 = 0.f, a6 = 0.f, a7 = 0.f;

    if (es == 0) {   // self-loop
        uint4 p = Tq[(unsigned)i * 8];
        a0 += bf_lo(p.x); a1 += bf_hi(p.x);
        a2 += bf_lo(p.y); a3 += bf_hi(p.y);
        a4 += bf_lo(p.z); a5 += bf_hi(p.z);
        a6 += bf_lo(p.w); a7 += bf_hi(p.w);
    }

    int pbeg = row_ptr[i], pend = row_ptr[i + 1];
    const int* cs = csr_src + pbeg + es;
    int nb8 = (pend - pbeg) >> 3;
    int full = nb8 >> 2;
    for (int t = 0; t < full; t++) {
        int s0 = cs[0], s1 = cs[8], s2 = cs[16], s3 = cs[24];
        cs += 32;
        uint4 p0 = Tq[(unsigned)s0 * 8];
        uint4 p1 = Tq[(unsigned)s1 * 8];
        uint4 p2 = Tq[(unsigned)s2 * 8];
        uint4 p3 = Tq[(unsigned)s3 * 8];
        a0 += bf_lo(p0.x) + bf_lo(p1.x); a1 += bf_hi(p0.x) + bf_hi(p1.x);
        a2 += bf_lo(p0.y) + bf_lo(p1.y); a3 += bf_hi(p0.y) + bf_hi(p1.y);
        a4 += bf_lo(p0.z) + bf_lo(p1.z); a5 += bf_hi(p0.z) + bf_hi(p1.z);
        a6 += bf_lo(p0.w) + bf_lo(p1.w); a7 += bf_hi(p0.w) + bf_hi(p1.w);
        a0 += bf_lo(p2.x) + bf_lo(p3.x); a1 += bf_hi(p2.x) + bf_hi(p3.x);
        a2 += bf_lo(p2.y) + bf_lo(p3.y); a3 += bf_hi(p2.y) + bf_hi(p3.y);
        a4 += bf_lo(p2.z) + bf_lo(p3.z); a5 += bf_hi(p2.z) + bf_hi(p3.z);
        a6 += bf_lo(p2.w) + bf_lo(p3.w); a7 += bf_hi(p2.w) + bf_hi(p3.w);
    }
    for (int rem = nb8 & 3; rem > 0; rem--) {
        int s = cs[0];
        cs += 8;
        uint4 p = Tq[(unsigned)s * 8];
        a0 += bf_lo(p.x); a1 += bf_hi(p.x);
        a2 += bf_lo(p.y); a3 += bf_hi(p.y);
        a4 += bf_lo(p.z); a5 += bf_hi(p.z);
        a6 += bf_lo(p.w); a7 += bf_hi(p.w);
    }

    // reduce over the 8 es slots (lanes sharing fg)
#pragma unroll
    for (int off = 8; off < 64; off <<= 1) {
        a0 += __shfl_xor(a0, off, 64);
        a1 += __shfl_xor(a1, off, 64);
        a2 += __shfl_xor(a2, off, 64);
        a3 += __shfl_xor(a3, off, 64);
        a4 += __shfl_xor(a4, off, 64);
        a5 += __shfl_xor(a5, off, 64);
        a6 += __shfl_xor(a6, off, 64);
        a7 += __shfl_xor(a7, off, 64);
    }

    float4 bb0 = ((const float4*)b)[fg * 2],    bb1 = ((const float4*)b)[fg * 2 + 1];
    float4 gg0 = ((const float4*)g)[fg * 2],    gg1 = ((const float4*)g)[fg * 2 + 1];
    float4 be0 = ((const float4*)beta)[fg * 2], be1 = ((const float4*)beta)[fg * 2 + 1];
    float4 mm0 = ((const float4*)m)[fg * 2],    mm1 = ((const float4*)m)[fg * 2 + 1];
    float4 vv0 = ((const float4*)v)[fg * 2],    vv1 = ((const float4*)v)[fg * 2 + 1];
    float di = dinv[i];
    float o0 = fmaxf((di * a0 + bb0.x - mm0.x) * (gg0.x * rsqrtf(vv0.x + BN_EPS_)) + be0.x, 0.f);
    float o1 = fmaxf((di * a1 + bb0.y - mm0.y) * (gg0.y * rsqrtf(vv0.y + BN_EPS_)) + be0.y, 0.f);
    float o2 = fmaxf((di * a2 + bb0.z - mm0.z) * (gg0.z * rsqrtf(vv0.z + BN_EPS_)) + be0.z, 0.f);
    float o3 = fmaxf((di * a3 + bb0.w - mm0.w) * (gg0.w * rsqrtf(vv0.w + BN_EPS_)) + be0.w, 0.f);
    float o4 = fmaxf((di * a4 + bb1.x - mm1.x) * (gg1.x * rsqrtf(vv1.x + BN_EPS_)) + be1.x, 0.f);
    float o5 = fmaxf((di * a5 + bb1.y - mm1.y) * (gg1.y * rsqrtf(vv1.y + BN_EPS_)) + be1.y, 0.f);
    float o6 = fmaxf((di * a6 + bb1.z - mm1.z) * (gg1.z * rsqrtf(vv1.z + BN_EPS_)) + be1.z, 0.f);
    float o7 = fmaxf((di * a7 + bb1.w - mm1.w) * (gg1.w * rsqrtf(vv1.w + BN_EPS_)) + be1.w, 0.f);

    if (LAST) {
        float4 w30 = ((const float4*)W3)[fg * 2], w31 = ((const float4*)W3)[fg * 2 + 1];
        float p = o0 * w30.x + o1 * w30.y + o2 * w30.z + o3 * w30.w +
                  o4 * w31.x + o5 * w31.y + o6 * w31.z + o7 * w31.w;
        // p is es-uniform; reduce over the 8 fg lanes only
#pragma unroll
        for (int off = 1; off < 8; off <<= 1)
            p += __shfl_xor(p, off, 64);
        if (l == 0) hs3[i] = p * di;
    } else {
        if (es == 0) {
            uint4 pk;
            pk.x = (unsigned)f2bf(o0) | ((unsigned)f2bf(o1) << 16);
            pk.y = (unsigned)f2bf(o2) | ((unsigned)f2bf(o3) << 16);
            pk.z = (unsigned)f2bf(o4) | ((unsigned)f2bf(o5) << 16);
            pk.w = (unsigned)f2bf(o6) | ((unsigned)f2bf(o7) << 16);
            ((uint4*)y)[(long)i * 8 + fg] = pk;
        }
    }
}

// --------- MFMA GEMM: hs(bf16, contiguous 128-B rows) = (X @ W) * dinv -----
// hs[node*64 + 16c + m] = feature 16c+m. Node N_NODES is a ZERO row.
template<int K, bool BF16IN>
__global__ __launch_bounds__(256) void gemm_bf16(const void* __restrict__ Xv,
                                                 const float* __restrict__ W,   // [K][64]
                                                 const float* __restrict__ dinv,
                                                 ushort* __restrict__ hs) {
    constexpr int KP = K + 8;
    __shared__ ushort A_lds[64][KP];
    __shared__ ushort Wt_lds[64][KP];
    int t = threadIdx.x;
    long row0 = (long)blockIdx.x * 64;

    for (int i = t; i < K * 16; i += 256) {
        float4 w4 = ((const float4*)W)[i];
        int k = i >> 4, n = (i & 15) * 4;
        Wt_lds[n + 0][k] = f2bf(w4.x);
        Wt_lds[n + 1][k] = f2bf(w4.y);
        Wt_lds[n + 2][k] = f2bf(w4.z);
        Wt_lds[n + 3][k] = f2bf(w4.w);
    }
    if (BF16IN) {
        constexpr int K2 = K / 2;
        const unsigned* X = (const unsigned*)Xv;
        for (int i = t; i < 64 * K2; i += 256) {
            int r = i / K2, c = i % K2;
            unsigned val = 0;
            long row = row0 + r;
            if (row < N_NODES) val = X[row * K2 + c];
            *(unsigned*)&A_lds[r][c * 2] = val;
        }
    } else {
        constexpr int K4 = K / 4;
        const float* X = (const float*)Xv;
        for (int i = t; i < 64 * K4; i += 256) {
            int r = i / K4, c = i % K4;
            float4 val = make_float4(0.f, 0.f, 0.f, 0.f);
            long row = row0 + r;
            if (row < N_NODES) val = ((const float4*)X)[row * K4 + c];
            int cb = c * 4;
            A_lds[r][cb + 0] = f2bf(val.x);
            A_lds[r][cb + 1] = f2bf(val.y);
            A_lds[r][cb + 2] = f2bf(val.z);
            A_lds[r][cb + 3] = f2bf(val.w);
        }
    }
    __syncthreads();

    int w = t >> 6, l = t & 63;
    int m = l & 15, quad = l >> 4;
    f32x4 acc[4];
#pragma unroll
    for (int c = 0; c < 4; c++) acc[c] = (f32x4){0.f, 0.f, 0.f, 0.f};

#pragma unroll
    for (int ch = 0; ch < K / 32; ch++) {
        short8 a = *(const short8*)&A_lds[16 * w + m][32 * ch + 8 * quad];
#pragma unroll
        for (int c = 0; c < 4; c++) {
            short8 b = *(const short8*)&Wt_lds[16 * c + m][32 * ch + 8 * quad];
            acc[c] = __builtin_amdgcn_mfma_f32_16x16x32_bf16(a, b, acc[c], 0, 0, 0);
        }
    }

#pragma unroll
    for (int r = 0; r < 4; r++) {
        long node = row0 + 16 * w + quad * 4 + r;
        if (node <= N_NODES) {                       // include zero row N
            float dv = (node < N_NODES) ? dinv[node] : 0.f;
#pragma unroll
            for (int c = 0; c < 4; c++)
                hs[node * 64 + 16 * c + m] = f2bf(acc[c][r] * dv);
        }
    }
}

// ---------------- layer-3 pull + sigmoid (padded rows, hs3[N]=0) -----------
__global__ __launch_bounds__(256) void gather3(const int* __restrict__ row_ptr,
                                               const int* __restrict__ csr_src,
                                               const float* __restrict__ hs3,
                                               const float* __restrict__ dinv,
                                               const float* __restrict__ b3,
                                               float* __restrict__ out, int n) {
    int i = blockIdx.x * 256 + threadIdx.x;
    if (i >= n) return;
    int beg = row_ptr[i], end = row_ptr[i + 1];
    float s0 = hs3[i], s1 = 0.f, s2 = 0.f, s3 = 0.f;
    float s4 = 0.f, s5 = 0.f, s6 = 0.f, s7 = 0.f;
    for (int k = beg; k + 8 <= end; k += 8) {
        s0 += hs3[csr_src[k]];
        s1 += hs3[csr_src[k + 1]];
        s2 += hs3[csr_src[k + 2]];
        s3 += hs3[csr_src[k + 3]];
        s4 += hs3[csr_src[k + 4]];
        s5 += hs3[csr_src[k + 5]];
        s6 += hs3[csr_src[k + 6]];
        s7 += hs3[csr_src[k + 7]];
    }
    float z = dinv[i] * (((s0 + s1) + (s2 + s3)) + ((s4 + s5) + (s6 + s7))) + b3[0];
    out[i] = 1.f / (1.f + expf(-z));
}

extern "C" void kernel_launch(void* const* d_in, const int* in_sizes, int n_in,
                              void* d_out, int out_size, void* d_ws, size_t ws_size,
                              hipStream_t stream) {
    const int N = N_NODES;
    const int E = E_EDGES;

    const float* x   = (const float*)d_in[0];
    const int*   ei  = (const int*)d_in[1];   // [2, E]: row0=src, row1=dst
    const float* W1  = (const float*)d_in[2];
    const float* b1  = (const float*)d_in[3];
    const float* W2  = (const float*)d_in[4];
    const float* b2  = (const float*)d_in[5];
    const float* W3  = (const float*)d_in[6];
    const float* b3  = (const float*)d_in[7];
    const float* g1  = (const float*)d_in[8];
    const float* bt1 = (const float*)d_in[9];
    const float* m1  = (const float*)d_in[10];
    const float* v1  = (const float*)d_in[11];
    const float* g2  = (const float*)d_in[12];
    const float* bt2 = (const float*)d_in[13];
    const float* m2  = (const float*)d_in[14];
    const float* v2  = (const float*)d_in[15];
    float* out = (float*)d_out;

    // workspace layout (4-byte units)
    int*    wsi          = (int*)d_ws;
    float*  dinv         = (float*)wsi;                       // N
    float*  hs3          = (float*)(wsi + (long)N);           // N+1 (pad 16)
    int*    row_ptr      = wsi + 2L * N + 16;                 // N+1 (pad 16)
    int*    deg          = row_ptr + N + 16;                  // N (pad 16)
    int*    histPB       = deg + N + 16;                      // NBUCK*PB = 97750
    int*    bucket_tot   = histPB + NBUCK * PB;               // 400
    int*    bucket_base  = bucket_tot + 400;                  // NBUCK+1 (pad 402)
    int*    bucket_ptot  = bucket_base + 402;                 // 400
    int*    bucket_pbase = bucket_ptot + 400;                 // 400 (+2 align)
    ushort* hsb          = (ushort*)(bucket_pbase + 402);     // (N+1)*64 bf16 = SUB*32 ints
    unsigned* yb         = (unsigned*)((int*)(void*)hsb + 32L * SUB); // N*32 uints
    int*    csr_src      = (int*)yb + 32L * N;                // padded: up to E+8N
    int*    ebuf         = (int*)(void*)hsb;                  // E ints, aliases hsb (build only)

    // ---- CSR build (bucketed counting sort, padded rows, no global atomics) --
    passA1_hist<<<PB, 512, 0, stream>>>(ei, histPB);
    scan_rows<<<NBUCK, 256, 0, stream>>>(histPB, bucket_tot);
    scan_totals<<<1, 512, 0, stream>>>(bucket_tot, bucket_base, hs3);
    passA2_sorted<<<PB, 512, 0, stream>>>(ei, histPB, bucket_base, ebuf);
    bucket_deg<<<NBUCK, 256, 0, stream>>>(ebuf, bucket_base, deg, dinv, bucket_ptot);
    scan_ptot<<<1, 512, 0, stream>>>(bucket_ptot, bucket_pbase, row_ptr);
    passB_sorted<<<NBUCK, 256, 0, stream>>>(ebuf, bucket_base, bucket_pbase,
                                            deg, row_ptr, csr_src);

    const int GG = (N + 3) / 4;   // one row per wave

    // ---- layer 1 ----
    gemm_bf16<IN_DIM_, false><<<(N + 63) / 64, 256, 0, stream>>>(x, W1, dinv, hsb);
    gather_full<false><<<GG, 256, 0, stream>>>(row_ptr, csr_src, hsb, dinv,
                                               b1, g1, bt1, m1, v1, yb, W3, hs3, N);
    // ---- layer 2 (+ fused gemv3) ----
    gemm_bf16<HID_, true><<<(N + 63) / 64, 256, 0, stream>>>(yb, W2, dinv, hsb);
    gather_full<true><<<GG, 256, 0, stream>>>(row_ptr, csr_src, hsb, dinv,
                                              b2, g2, bt2, m2, v2, yb, W3, hs3, N);
    // ---- layer 3 ----
    gather3<<<(N + 255) / 256, 256, 0, stream>>>(row_ptr, csr_src, hs3, dinv, b3, out, N);
}